// Round 1
// baseline (1074.327 us; speedup 1.0000x reference)
//
#include <hip/hip_runtime.h>

// Sinkhorn (WlossLayer): B=65536 rows, na=nb=128, lam=100, eps=1e-8.
// Reference runs <=50 iters with early stop at rel-change < 1e-8; K=exp(-cost/100)
// has Hilbert contraction <= 0.005/iter, so 12 fixed iterations reach the same
// fp32 fixed point as the reference regardless of where it stops.
//
// Layouts (per wave, R=8 rows):
//   matvec1 output (log_v / v_stab): col = 4*(lane&31) + t      ("layout A")
//   matvec2 output (log_u / grad):   col = (lane&31) + 32*t     ("layout B")
//   log_b loaded in layout A, log_a in layout B.
// Half-wave split over reduction axis: lanes 0-31 take j in [0,64),
// lanes 32-63 take j in [64,128); one shfl_xor(32) combines partials.
//
// K in LDS with a 16B-granule XOR swizzle keyed on row bits 3..5 so BOTH
// matvec read patterns (same-row b128, and rows c+32t at a fixed column) are
// bank-conflict-free AND 16B-aligned (a +1-word pad would misalign float4).

constexpr int BROWS = 65536;
constexpr int NN    = 128;
constexpr int NITER = 12;
constexpr int R     = 8;     // rows per wave
constexpr int NWAVE = 8;     // waves per block
constexpr int BLOCK = NWAVE * 64;          // 512 threads
constexpr int ROWS_PER_BLOCK = NWAVE * R;  // 64
constexpr float LAMF = 100.0f;
constexpr float EPSF = 1e-8f;
constexpr float NEG_LOG_N = -4.852030263919617f;  // -log(128)

__device__ __forceinline__ int kidx(int j, int i) {
  // word index into Ks[128*128]; XOR on word bits 2..4 keyed by row bits 3..5
  return j * NN + (i ^ (((j >> 3) & 7) << 2));
}

__device__ __forceinline__ void mv1_step(float (&a)[4], const float4 u4,
                                         const float4 k0, const float4 k1,
                                         const float4 k2, const float4 k3) {
  // a[t] += sum_q u4[q] * k_q[t]   (k_q = K row j+q, 4 consecutive cols)
  a[0] = fmaf(u4.x, k0.x, fmaf(u4.y, k1.x, fmaf(u4.z, k2.x, fmaf(u4.w, k3.x, a[0]))));
  a[1] = fmaf(u4.x, k0.y, fmaf(u4.y, k1.y, fmaf(u4.z, k2.y, fmaf(u4.w, k3.y, a[1]))));
  a[2] = fmaf(u4.x, k0.z, fmaf(u4.y, k1.z, fmaf(u4.z, k2.z, fmaf(u4.w, k3.z, a[2]))));
  a[3] = fmaf(u4.x, k0.w, fmaf(u4.y, k1.w, fmaf(u4.z, k2.w, fmaf(u4.w, k3.w, a[3]))));
}

__device__ __forceinline__ void mv2_step(float (&a)[4], const float4 v4,
                                         const float4 r0, const float4 r1,
                                         const float4 r2, const float4 r3) {
  // a[t] += dot(v4, row_t[i..i+3])  (row_t = K row c+32t)
  a[0] = fmaf(v4.x, r0.x, fmaf(v4.y, r0.y, fmaf(v4.z, r0.z, fmaf(v4.w, r0.w, a[0]))));
  a[1] = fmaf(v4.x, r1.x, fmaf(v4.y, r1.y, fmaf(v4.z, r1.z, fmaf(v4.w, r1.w, a[1]))));
  a[2] = fmaf(v4.x, r2.x, fmaf(v4.y, r2.y, fmaf(v4.z, r2.z, fmaf(v4.w, r2.w, a[2]))));
  a[3] = fmaf(v4.x, r3.x, fmaf(v4.y, r3.y, fmaf(v4.z, r3.z, fmaf(v4.w, r3.w, a[3]))));
}

__global__ __launch_bounds__(BLOCK, 2)
void sink_main(const float* __restrict__ pred,
               const float* __restrict__ tgt,
               const float* __restrict__ cost,
               float* __restrict__ out,
               float* __restrict__ ws)
{
  __shared__ float Ks[NN * NN];            // 64 KB, swizzled
  __shared__ float UV[NWAVE][R][NN];       // 32 KB, u_stab / v_stab per wave
  __shared__ float wred[NWAVE];

  const int tid  = threadIdx.x;
  const int wv   = tid >> 6;
  const int lane = tid & 63;
  const int c    = lane & 31;
  const int half = lane >> 5;
  const int jb   = half * 64;

  // K = exp(-cost/lam)
  for (int idx = tid; idx < NN * NN; idx += BLOCK) {
    const int j = idx >> 7, i = idx & (NN - 1);
    Ks[kidx(j, i)] = expf(-cost[idx] / LAMF);
  }
  __syncthreads();

  const int row0 = blockIdx.x * ROWS_PER_BLOCK + wv * R;

  float la[R][4], lb[R][4], lu[R][4], mu[R], mv[R];
#pragma unroll
  for (int r = 0; r < R; ++r) {
#pragma unroll
    for (int t = 0; t < 4; ++t) {
      la[r][t] = logf(pred[(row0 + r) * NN + (c + 32 * t)] + EPSF);
      lb[r][t] = logf(tgt [(row0 + r) * NN + (4 * c + t)] + EPSF);
    }
    mu[r] = NEG_LOG_N;
  }

  // u_stab(iter0) = exp(log_u0 - max + EPS) = exp(1e-8) = 1.0f
  if (lane < 32) {
#pragma unroll
    for (int r = 0; r < R; ++r)
      *reinterpret_cast<float4*>(&UV[wv][r][4 * c]) = make_float4(1.f, 1.f, 1.f, 1.f);
  }

  for (int it = 0; it < NITER; ++it) {
    // ---- matvec1: S_v[4c+t] = sum_j u[j] * K[j][4c+t]
    float acc[R][4];
#pragma unroll
    for (int r = 0; r < R; ++r)
      acc[r][0] = acc[r][1] = acc[r][2] = acc[r][3] = 0.f;

    for (int j0 = 0; j0 < 64; j0 += 4) {
      const int j = jb + j0;
      const float4 k0 = *reinterpret_cast<const float4*>(&Ks[kidx(j + 0, 4 * c)]);
      const float4 k1 = *reinterpret_cast<const float4*>(&Ks[kidx(j + 1, 4 * c)]);
      const float4 k2 = *reinterpret_cast<const float4*>(&Ks[kidx(j + 2, 4 * c)]);
      const float4 k3 = *reinterpret_cast<const float4*>(&Ks[kidx(j + 3, 4 * c)]);
#pragma unroll
      for (int r = 0; r < R; ++r) {
        const float4 u4 = *reinterpret_cast<const float4*>(&UV[wv][r][j]);
        mv1_step(acc[r], u4, k0, k1, k2, k3);
      }
    }
#pragma unroll
    for (int r = 0; r < R; ++r)
#pragma unroll
      for (int t = 0; t < 4; ++t) {
        const float o = __shfl_xor(acc[r][t], 32);
        acc[r][t] += o;
      }

    // log_v = log_b - log(S_v) - m_u ; m_v = rowmax ; v_stab = exp(log_v - m_v)
#pragma unroll
    for (int r = 0; r < R; ++r) {
      float m = -3.0e38f;
#pragma unroll
      for (int t = 0; t < 4; ++t) {
        const float lv = lb[r][t] - logf(acc[r][t]) - mu[r];
        acc[r][t] = lv;
        m = fmaxf(m, lv);
      }
      m = fmaxf(m, __shfl_xor(m, 1));
      m = fmaxf(m, __shfl_xor(m, 2));
      m = fmaxf(m, __shfl_xor(m, 4));
      m = fmaxf(m, __shfl_xor(m, 8));
      m = fmaxf(m, __shfl_xor(m, 16));
      mv[r] = m;
#pragma unroll
      for (int t = 0; t < 4; ++t) acc[r][t] = expf(acc[r][t] - mv[r]);
    }
    if (lane < 32) {
#pragma unroll
      for (int r = 0; r < R; ++r)
        *reinterpret_cast<float4*>(&UV[wv][r][4 * c]) =
            make_float4(acc[r][0], acc[r][1], acc[r][2], acc[r][3]);
    }

    // ---- matvec2: S_u[c+32t] = sum_i v[i] * K[c+32t][i]
    float ac2[R][4];
#pragma unroll
    for (int r = 0; r < R; ++r)
      ac2[r][0] = ac2[r][1] = ac2[r][2] = ac2[r][3] = 0.f;

    for (int i0 = 0; i0 < 64; i0 += 4) {
      const int i = jb + i0;
      const float4 r0 = *reinterpret_cast<const float4*>(&Ks[kidx(c +  0, i)]);
      const float4 r1 = *reinterpret_cast<const float4*>(&Ks[kidx(c + 32, i)]);
      const float4 r2 = *reinterpret_cast<const float4*>(&Ks[kidx(c + 64, i)]);
      const float4 r3 = *reinterpret_cast<const float4*>(&Ks[kidx(c + 96, i)]);
#pragma unroll
      for (int r = 0; r < R; ++r) {
        const float4 v4 = *reinterpret_cast<const float4*>(&UV[wv][r][i]);
        mv2_step(ac2[r], v4, r0, r1, r2, r3);
      }
    }
#pragma unroll
    for (int r = 0; r < R; ++r)
#pragma unroll
      for (int t = 0; t < 4; ++t) {
        const float o = __shfl_xor(ac2[r][t], 32);
        ac2[r][t] += o;
      }

    // log_u = log_a - log(S_u + EPS) - m_v ; m_u = rowmax
#pragma unroll
    for (int r = 0; r < R; ++r) {
      float m = -3.0e38f;
#pragma unroll
      for (int t = 0; t < 4; ++t) {
        const float l = la[r][t] - logf(ac2[r][t] + EPSF) - mv[r];
        lu[r][t] = l;
        m = fmaxf(m, l);
      }
      m = fmaxf(m, __shfl_xor(m, 1));
      m = fmaxf(m, __shfl_xor(m, 2));
      m = fmaxf(m, __shfl_xor(m, 4));
      m = fmaxf(m, __shfl_xor(m, 8));
      m = fmaxf(m, __shfl_xor(m, 16));
      mu[r] = m;
    }

    if (it < NITER - 1) {
      // u_stab = exp(log_u - m_u + EPS), layout B (stride-32 b32 writes, conflict-free)
      if (lane < 32) {
#pragma unroll
        for (int r = 0; r < R; ++r)
#pragma unroll
          for (int t = 0; t < 4; ++t)
            UV[wv][r][c + 32 * t] = expf(lu[r][t] - mu[r] + EPSF);
      }
    }
  }

  // ---- finalization: KM = cost*K = K * (-lam * log K), elementwise in place
  __syncthreads();
  for (int idx = tid; idx < NN * NN; idx += BLOCK) {
    const float k = Ks[idx];
    Ks[idx] = k * (-LAMF * logf(k));
  }
  __syncthreads();

  // t[c+32t] = sum_i v_stab[i] * KM[c+32t][i]   (v_stab still in UV)
  float ac2[R][4];
#pragma unroll
  for (int r = 0; r < R; ++r)
    ac2[r][0] = ac2[r][1] = ac2[r][2] = ac2[r][3] = 0.f;

  for (int i0 = 0; i0 < 64; i0 += 4) {
    const int i = jb + i0;
    const float4 r0 = *reinterpret_cast<const float4*>(&Ks[kidx(c +  0, i)]);
    const float4 r1 = *reinterpret_cast<const float4*>(&Ks[kidx(c + 32, i)]);
    const float4 r2 = *reinterpret_cast<const float4*>(&Ks[kidx(c + 64, i)]);
    const float4 r3 = *reinterpret_cast<const float4*>(&Ks[kidx(c + 96, i)]);
#pragma unroll
    for (int r = 0; r < R; ++r) {
      const float4 v4 = *reinterpret_cast<const float4*>(&UV[wv][r][i]);
      mv2_step(ac2[r], v4, r0, r1, r2, r3);
    }
  }
#pragma unroll
  for (int r = 0; r < R; ++r)
#pragma unroll
    for (int t = 0; t < 4; ++t) {
      const float o = __shfl_xor(ac2[r][t], 32);
      ac2[r][t] += o;
    }

  // wnorm partial: sum exp(log_u + log(t+EPS) + m_v)
  float wsum = 0.f;
#pragma unroll
  for (int r = 0; r < R; ++r)
#pragma unroll
    for (int t = 0; t < 4; ++t) {
      const float lc = logf(ac2[r][t] + EPSF) + mv[r];
      wsum += expf(lu[r][t] + lc);
    }
  wsum += __shfl_xor(wsum, 1);
  wsum += __shfl_xor(wsum, 2);
  wsum += __shfl_xor(wsum, 4);
  wsum += __shfl_xor(wsum, 8);
  wsum += __shfl_xor(wsum, 16);
  wsum += __shfl_xor(wsum, 32);
  if (lane == 0) wred[wv] = wsum * 0.5f;  // halves are exact duplicates

  // grad = (log_u - rowmean(log_u)) * lam / B
#pragma unroll
  for (int r = 0; r < R; ++r) {
    float s = lu[r][0] + lu[r][1] + lu[r][2] + lu[r][3];
    s += __shfl_xor(s, 1);
    s += __shfl_xor(s, 2);
    s += __shfl_xor(s, 4);
    s += __shfl_xor(s, 8);
    s += __shfl_xor(s, 16);
    const float meanv = s * (1.0f / 128.0f);
    if (lane < 32) {
#pragma unroll
      for (int t = 0; t < 4; ++t)
        out[1 + (row0 + r) * NN + (c + 32 * t)] =
            (lu[r][t] - meanv) * (LAMF / (float)BROWS);
    }
  }

  __syncthreads();
  if (tid == 0) {
    float s = 0.f;
#pragma unroll
    for (int w = 0; w < NWAVE; ++w) s += wred[w];
    ws[blockIdx.x] = s;
  }
}

__global__ void sink_reduce(const float* __restrict__ ws,
                            float* __restrict__ out, int nblocks)
{
  float s = 0.f;
  for (int i = threadIdx.x; i < nblocks; i += 256) s += ws[i];
  s += __shfl_xor(s, 1);
  s += __shfl_xor(s, 2);
  s += __shfl_xor(s, 4);
  s += __shfl_xor(s, 8);
  s += __shfl_xor(s, 16);
  s += __shfl_xor(s, 32);
  __shared__ float sm[4];
  if ((threadIdx.x & 63) == 0) sm[threadIdx.x >> 6] = s;
  __syncthreads();
  if (threadIdx.x == 0)
    out[0] = (sm[0] + sm[1] + sm[2] + sm[3]) * (1.0f / (float)BROWS);
}

extern "C" void kernel_launch(void* const* d_in, const int* in_sizes, int n_in,
                              void* d_out, int out_size, void* d_ws, size_t ws_size,
                              hipStream_t stream)
{
  const float* pred = (const float*)d_in[0];
  const float* tgt  = (const float*)d_in[1];
  const float* cost = (const float*)d_in[2];
  float* out = (float*)d_out;
  float* ws  = (float*)d_ws;

  const int nblocks = BROWS / ROWS_PER_BLOCK;  // 1024
  sink_main<<<nblocks, BLOCK, 0, stream>>>(pred, tgt, cost, out, ws);
  sink_reduce<<<1, 256, 0, stream>>>(ws, out, nblocks);
}

// Round 2
// 473.862 us; speedup vs baseline: 2.2672x; 2.2672x over previous
//
#include <hip/hip_runtime.h>

// Sinkhorn via MFMA. K = exp(-cost/100) = 1 + E, |E| <= 0.00995.
//   u@K = sum(u) + u@E  -> bf16 MFMA only carries the 0.5% correction term.
// Chained-transpose formulation (all per-iteration data stays in registers):
//   MV1: Sv^T = E^T(LDS) x U^T(regs) ; MV2: Su^T = E(LDS) x V^T(regs)
//   D-layout of each stage == B-frag layout of the next (16x16x32 bf16).
// Base-2 logs/exps throughout (v_log_f32 / v_exp_f32). 8 iterations reach the
// reference's fixed point (contraction <= 0.005/iter).

typedef __attribute__((ext_vector_type(4))) float f32x4;
typedef __attribute__((ext_vector_type(4))) short s16x4;
typedef __attribute__((ext_vector_type(8))) short s16x8;

constexpr int   NITER = 8;
constexpr float EPSF  = 1e-8f;
constexpr float LOG2E = 1.44269504088896340736f;
constexpr float LN2   = 0.69314718055994530942f;
constexpr float GRADS = LN2 * 100.0f / 65536.0f;   // ln2 * lam / B

__device__ __forceinline__ unsigned short f2bf(float x) {
  unsigned u = __builtin_bit_cast(unsigned, x);
  u += 0x7fffu + ((u >> 16) & 1u);
  return (unsigned short)(u >> 16);
}
__device__ __forceinline__ float bf2f(unsigned short h) {
  return __builtin_bit_cast(float, (unsigned)h << 16);
}

// word index of element (r,c) of a 128x128 bf16 matrix, row-major, with a
// granule(8B)-XOR swizzle keyed on row bits 0..2 -> A-frag reads are
// conflict-free (4 words/bank per ds_read_b64 instruction).
__device__ __forceinline__ int swzw(int r, int c) {
  return (r << 7) + ((((c >> 2) ^ ((r & 7) << 2)) << 2) | (c & 3));
}

// A-fragment (16x16x32 bf16): lane row = (l&15)+16*mt, k = (j&3)+4*h+16*(j>>2)+32*s
__device__ __forceinline__ s16x8 afrag(const short* M, int row, int kb, int h) {
  const int base = (row << 7) + ((((kb >> 2) + h) ^ ((row & 7) << 2)) << 2);
  const s16x4 lo = *reinterpret_cast<const s16x4*>(M + base);
  const s16x4 hi = *reinterpret_cast<const s16x4*>(M + (base ^ 16));
  s16x8 r;
  r[0] = lo[0]; r[1] = lo[1]; r[2] = lo[2]; r[3] = lo[3];
  r[4] = hi[0]; r[5] = hi[1]; r[6] = hi[2]; r[7] = hi[3];
  return r;
}

__device__ __forceinline__ s16x8 packb(const f32x4 a, const f32x4 b) {
  s16x8 r;
  r[0] = (short)f2bf(a[0]); r[1] = (short)f2bf(a[1]);
  r[2] = (short)f2bf(a[2]); r[3] = (short)f2bf(a[3]);
  r[4] = (short)f2bf(b[0]); r[5] = (short)f2bf(b[1]);
  r[6] = (short)f2bf(b[2]); r[7] = (short)f2bf(b[3]);
  return r;
}

__global__ __launch_bounds__(256, 2)
void sink_mfma(const float* __restrict__ pred,
               const float* __restrict__ tgt,
               const float* __restrict__ cost,
               float* __restrict__ out,
               float* __restrict__ ws)
{
  __shared__ __align__(16) short EA[128 * 128]; // E^T: row i, col j (MV1 A)
  __shared__ __align__(16) short EB[128 * 128]; // E  : row j, col i (MV2 A)
  __shared__ float wred[4];

  const int tid  = threadIdx.x;
  const int lane = tid & 63;
  const int wv   = tid >> 6;
  const int cl   = lane & 15;
  const int h    = lane >> 4;
  const float c1 = LOG2E * 0.01f;  // K = 2^(-cost*c1)

  // ---- stage E = K - 1 (bf16) into both LDS layouts
  for (int idx = tid; idx < 128 * 128; idx += 256) {
    const int j = idx >> 7, i = idx & 127;
    const float e = __builtin_amdgcn_exp2f(-cost[idx] * c1) - 1.0f;
    const short eb = (short)f2bf(e);
    EB[swzw(j, i)] = eb;
    EA[swzw(i, j)] = eb;
  }
  __syncthreads();

  const int row0 = (blockIdx.x << 7) + (wv << 5);  // 32 rows per wave

  // ---- logs of inputs, directly in the MFMA D layouts
  f32x4 l2a[2][8], l2b[2][8];
#pragma unroll
  for (int nt = 0; nt < 2; ++nt)
#pragma unroll
    for (int mt = 0; mt < 8; ++mt) {
      const int rr = (row0 + cl + (nt << 4)) << 7;
      const float4 va = *reinterpret_cast<const float4*>(&pred[rr + (mt << 4) + (h << 2)]);
      const float4 vb = *reinterpret_cast<const float4*>(&tgt [rr + (mt << 4) + (h << 2)]);
      f32x4 ta, tb;
      ta[0] = __builtin_amdgcn_logf(va.x + EPSF); ta[1] = __builtin_amdgcn_logf(va.y + EPSF);
      ta[2] = __builtin_amdgcn_logf(va.z + EPSF); ta[3] = __builtin_amdgcn_logf(va.w + EPSF);
      tb[0] = __builtin_amdgcn_logf(vb.x + EPSF); tb[1] = __builtin_amdgcn_logf(vb.y + EPSF);
      tb[2] = __builtin_amdgcn_logf(vb.z + EPSF); tb[3] = __builtin_amdgcn_logf(vb.w + EPSF);
      l2a[nt][mt] = ta;
      l2b[nt][mt] = tb;
    }

  // ---- state
  s16x8 uf[4][2], vf[4][2];
  {
    s16x8 ones;
#pragma unroll
    for (int k = 0; k < 8; ++k) ones[k] = (short)0x3F80;  // bf16 1.0
#pragma unroll
    for (int s = 0; s < 4; ++s) { uf[s][0] = ones; uf[s][1] = ones; }
  }
  float sum_u[2] = {128.0f, 128.0f};
  float m2u[2]   = {-7.0f, -7.0f};   // log2(1/128)
  float m2v[2], sum_v[2];
  f32x4 X[8][2];

  for (int it = 0; it < NITER; ++it) {
    // ======== MV1: X = E^T x U^T  (then Sv = sum_u + X) ========
#pragma unroll
    for (int mt = 0; mt < 8; ++mt) { X[mt][0] = f32x4{0,0,0,0}; X[mt][1] = f32x4{0,0,0,0}; }
#pragma unroll
    for (int s = 0; s < 4; ++s)
#pragma unroll
      for (int mt = 0; mt < 8; ++mt) {
        const s16x8 a = afrag(EA, cl + (mt << 4), s << 5, h);
        X[mt][0] = __builtin_amdgcn_mfma_f32_16x16x32_bf16(a, uf[s][0], X[mt][0], 0, 0, 0);
        X[mt][1] = __builtin_amdgcn_mfma_f32_16x16x32_bf16(a, uf[s][1], X[mt][1], 0, 0, 0);
      }
    // stage1 finish: l2v = l2b - log2(Sv) - m2u ; m2v ; v = 2^(l2v-m2v) ; sum_v
#pragma unroll
    for (int nt = 0; nt < 2; ++nt) {
      float m = -3.0e38f;
#pragma unroll
      for (int mt = 0; mt < 8; ++mt)
#pragma unroll
        for (int q = 0; q < 4; ++q) {
          const float lv = l2b[nt][mt][q]
                         - __builtin_amdgcn_logf(sum_u[nt] + X[mt][nt][q])
                         - m2u[nt];
          X[mt][nt][q] = lv;
          m = fmaxf(m, lv);
        }
      m = fmaxf(m, __shfl_xor(m, 16));
      m = fmaxf(m, __shfl_xor(m, 32));
      m2v[nt] = m;
      float sv = 0.f;
#pragma unroll
      for (int mt = 0; mt < 8; ++mt)
#pragma unroll
        for (int q = 0; q < 4; ++q) {
          const float v = __builtin_amdgcn_exp2f(X[mt][nt][q] - m);
          X[mt][nt][q] = v;
          sv += v;
        }
      sv += __shfl_xor(sv, 16);
      sv += __shfl_xor(sv, 32);
      sum_v[nt] = sv;
    }
#pragma unroll
    for (int s = 0; s < 4; ++s) {
      vf[s][0] = packb(X[2 * s][0], X[2 * s + 1][0]);
      vf[s][1] = packb(X[2 * s][1], X[2 * s + 1][1]);
    }

    // ======== MV2: X = E x V^T  (then Su = sum_v + X) ========
#pragma unroll
    for (int mt = 0; mt < 8; ++mt) { X[mt][0] = f32x4{0,0,0,0}; X[mt][1] = f32x4{0,0,0,0}; }
#pragma unroll
    for (int s = 0; s < 4; ++s)
#pragma unroll
      for (int mt = 0; mt < 8; ++mt) {
        const s16x8 a = afrag(EB, cl + (mt << 4), s << 5, h);
        X[mt][0] = __builtin_amdgcn_mfma_f32_16x16x32_bf16(a, vf[s][0], X[mt][0], 0, 0, 0);
        X[mt][1] = __builtin_amdgcn_mfma_f32_16x16x32_bf16(a, vf[s][1], X[mt][1], 0, 0, 0);
      }
    // stage2 finish: l2u = l2a - log2(Su + EPS) - m2v ; m2u
#pragma unroll
    for (int nt = 0; nt < 2; ++nt) {
      float m = -3.0e38f;
#pragma unroll
      for (int mt = 0; mt < 8; ++mt)
#pragma unroll
        for (int q = 0; q < 4; ++q) {
          const float lu = l2a[nt][mt][q]
                         - __builtin_amdgcn_logf(sum_v[nt] + X[mt][nt][q] + EPSF)
                         - m2v[nt];
          X[mt][nt][q] = lu;
          m = fmaxf(m, lu);
        }
      m = fmaxf(m, __shfl_xor(m, 16));
      m = fmaxf(m, __shfl_xor(m, 32));
      m2u[nt] = m;
    }
    if (it < NITER - 1) {
#pragma unroll
      for (int nt = 0; nt < 2; ++nt) {
        float su = 0.f;
#pragma unroll
        for (int s = 0; s < 4; ++s) {
          f32x4 ua, ub;
#pragma unroll
          for (int q = 0; q < 4; ++q) {
            ua[q] = __builtin_amdgcn_exp2f(X[2 * s][nt][q] - m2u[nt]);
            su += ua[q];
          }
#pragma unroll
          for (int q = 0; q < 4; ++q) {
            ub[q] = __builtin_amdgcn_exp2f(X[2 * s + 1][nt][q] - m2u[nt]);
            su += ub[q];
          }
          uf[s][nt] = packb(ua, ub);
        }
        su += __shfl_xor(su, 16);
        su += __shfl_xor(su, 32);
        sum_u[nt] = su;
      }
    }
  }

  // ======== final: T = KM x V^T with KM = hi + lo bf16 split ========
  __syncthreads();
  for (int idx = tid; idx < 128 * 128; idx += 256) {
    const int j = idx >> 7, i = idx & 127;
    const float cst = cost[idx];
    const float km  = cst * __builtin_amdgcn_exp2f(-cst * c1);
    const unsigned short khi = f2bf(km);
    const unsigned short klo = f2bf(km - bf2f(khi));
    const int w = swzw(j, i);
    EB[w] = (short)khi;
    EA[w] = (short)klo;
  }
  __syncthreads();

  f32x4 T[8][2];
#pragma unroll
  for (int mt = 0; mt < 8; ++mt) { T[mt][0] = f32x4{0,0,0,0}; T[mt][1] = f32x4{0,0,0,0}; }
#pragma unroll
  for (int s = 0; s < 4; ++s)
#pragma unroll
    for (int mt = 0; mt < 8; ++mt) {
      const s16x8 ahi = afrag(EB, cl + (mt << 4), s << 5, h);
      const s16x8 alo = afrag(EA, cl + (mt << 4), s << 5, h);
      T[mt][0] = __builtin_amdgcn_mfma_f32_16x16x32_bf16(ahi, vf[s][0], T[mt][0], 0, 0, 0);
      T[mt][0] = __builtin_amdgcn_mfma_f32_16x16x32_bf16(alo, vf[s][0], T[mt][0], 0, 0, 0);
      T[mt][1] = __builtin_amdgcn_mfma_f32_16x16x32_bf16(ahi, vf[s][1], T[mt][1], 0, 0, 0);
      T[mt][1] = __builtin_amdgcn_mfma_f32_16x16x32_bf16(alo, vf[s][1], T[mt][1], 0, 0, 0);
    }

  // wnorm partial: sum 2^(l2u + log2(T+EPS) + m2v)
  float wsum = 0.f;
#pragma unroll
  for (int nt = 0; nt < 2; ++nt)
#pragma unroll
    for (int mt = 0; mt < 8; ++mt)
#pragma unroll
      for (int q = 0; q < 4; ++q)
        wsum += __builtin_amdgcn_exp2f(X[mt][nt][q]
                  + __builtin_amdgcn_logf(T[mt][nt][q] + EPSF) + m2v[nt]);
  wsum += __shfl_xor(wsum, 1);
  wsum += __shfl_xor(wsum, 2);
  wsum += __shfl_xor(wsum, 4);
  wsum += __shfl_xor(wsum, 8);
  wsum += __shfl_xor(wsum, 16);
  wsum += __shfl_xor(wsum, 32);
  if (lane == 0) wred[wv] = wsum;

  // grad = (l2u - rowmean) * ln2 * lam / B
#pragma unroll
  for (int nt = 0; nt < 2; ++nt) {
    float sm = 0.f;
#pragma unroll
    for (int mt = 0; mt < 8; ++mt)
#pragma unroll
      for (int q = 0; q < 4; ++q) sm += X[mt][nt][q];
    sm += __shfl_xor(sm, 16);
    sm += __shfl_xor(sm, 32);
    const float mean = sm * 0.0078125f;
    const int rr = 1 + ((row0 + cl + (nt << 4)) << 7) + (h << 2);
#pragma unroll
    for (int mt = 0; mt < 8; ++mt)
#pragma unroll
      for (int q = 0; q < 4; ++q)
        out[rr + (mt << 4) + q] = (X[mt][nt][q] - mean) * GRADS;
  }

  __syncthreads();
  if (tid == 0) ws[blockIdx.x] = wred[0] + wred[1] + wred[2] + wred[3];
}

__global__ void sink_reduce(const float* __restrict__ ws, float* __restrict__ out)
{
  float s = 0.f;
  for (int i = threadIdx.x; i < 512; i += 256) s += ws[i];
  s += __shfl_xor(s, 1);
  s += __shfl_xor(s, 2);
  s += __shfl_xor(s, 4);
  s += __shfl_xor(s, 8);
  s += __shfl_xor(s, 16);
  s += __shfl_xor(s, 32);
  __shared__ float sm[4];
  if ((threadIdx.x & 63) == 0) sm[threadIdx.x >> 6] = s;
  __syncthreads();
  if (threadIdx.x == 0) out[0] = (sm[0] + sm[1] + sm[2] + sm[3]) * (1.0f / 65536.0f);
}

extern "C" void kernel_launch(void* const* d_in, const int* in_sizes, int n_in,
                              void* d_out, int out_size, void* d_ws, size_t ws_size,
                              hipStream_t stream)
{
  const float* pred = (const float*)d_in[0];
  const float* tgt  = (const float*)d_in[1];
  const float* cost = (const float*)d_in[2];
  float* out = (float*)d_out;
  float* ws  = (float*)d_ws;

  sink_mfma<<<512, 256, 0, stream>>>(pred, tgt, cost, out, ws);
  sink_reduce<<<1, 256, 0, stream>>>(ws, out);
}

// Round 3
// 410.949 us; speedup vs baseline: 2.6143x; 1.1531x over previous
//
#include <hip/hip_runtime.h>

// Sinkhorn via MFMA. K = exp(-cost/100) = 1 + E, |E| <= 0.00995.
//   u@K = sum(u) + u@E  -> bf16 MFMA only carries the 0.5% correction term.
// Chained-transpose formulation (all per-iteration data stays in registers):
//   MV1: Sv^T = E^T(LDS) x U^T(regs) ; MV2: Su^T = E(LDS) x V^T(regs)
//   D-layout of each stage == B-frag layout of the next (16x16x32 bf16).
// Base-2 logs/exps throughout (v_log_f32 / v_exp_f32 semantics). 8 iterations
// reach the reference's fixed point (Hilbert contraction ~0.0025/iter).
//
// Round-3 change: 16 batch-rows per wave (was 32) -> per-lane register state
// ~170 VGPR, no scratch spill (round 2 spilled ~800 MB/launch to HBM).

typedef __attribute__((ext_vector_type(4))) float f32x4;
typedef __attribute__((ext_vector_type(4))) short s16x4;
typedef __attribute__((ext_vector_type(8))) short s16x8;

constexpr int   NITER = 8;
constexpr float EPSF  = 1e-8f;
constexpr float LOG2E = 1.44269504088896340736f;
constexpr float LN2   = 0.69314718055994530942f;
constexpr float GRADS = LN2 * 100.0f / 65536.0f;   // ln2 * lam / B

__device__ __forceinline__ unsigned short f2bf(float x) {
  unsigned u = __builtin_bit_cast(unsigned, x);
  u += 0x7fffu + ((u >> 16) & 1u);
  return (unsigned short)(u >> 16);
}
__device__ __forceinline__ float bf2f(unsigned short h) {
  return __builtin_bit_cast(float, (unsigned)h << 16);
}

// word index of element (r,c) of a 128x128 bf16 matrix, row-major, with a
// granule(8B)-XOR swizzle keyed on row bits 0..2 -> A-frag reads are
// conflict-free.
__device__ __forceinline__ int swzw(int r, int c) {
  return (r << 7) + ((((c >> 2) ^ ((r & 7) << 2)) << 2) | (c & 3));
}

// A-fragment (16x16x32 bf16): lane row r, k = (j&3)+4*h+16*(j>>2)+32*s
__device__ __forceinline__ s16x8 afrag(const short* M, int row, int kb, int h) {
  const int base = (row << 7) + ((((kb >> 2) + h) ^ ((row & 7) << 2)) << 2);
  const s16x4 lo = *reinterpret_cast<const s16x4*>(M + base);
  const s16x4 hi = *reinterpret_cast<const s16x4*>(M + (base ^ 16));
  s16x8 r;
  r[0] = lo[0]; r[1] = lo[1]; r[2] = lo[2]; r[3] = lo[3];
  r[4] = hi[0]; r[5] = hi[1]; r[6] = hi[2]; r[7] = hi[3];
  return r;
}

__device__ __forceinline__ s16x8 packb(const f32x4 a, const f32x4 b) {
  s16x8 r;
  r[0] = (short)f2bf(a[0]); r[1] = (short)f2bf(a[1]);
  r[2] = (short)f2bf(a[2]); r[3] = (short)f2bf(a[3]);
  r[4] = (short)f2bf(b[0]); r[5] = (short)f2bf(b[1]);
  r[6] = (short)f2bf(b[2]); r[7] = (short)f2bf(b[3]);
  return r;
}

__global__ __launch_bounds__(256, 2)
void sink_mfma(const float* __restrict__ pred,
               const float* __restrict__ tgt,
               const float* __restrict__ cost,
               float* __restrict__ out,
               float* __restrict__ ws)
{
  __shared__ __align__(16) short EA[128 * 128]; // E^T: row i, col j (MV1 A)
  __shared__ __align__(16) short EB[128 * 128]; // E  : row j, col i (MV2 A)
  __shared__ float wred[4];

  const int tid  = threadIdx.x;
  const int lane = tid & 63;
  const int wv   = tid >> 6;
  const int cl   = lane & 15;
  const int h    = lane >> 4;
  const float c1 = LOG2E * 0.01f;  // K = 2^(-cost*c1)

  // ---- stage E = K - 1 (bf16) into both LDS layouts
  for (int idx = tid; idx < 128 * 128; idx += 256) {
    const int j = idx >> 7, i = idx & 127;
    const float e = __builtin_amdgcn_exp2f(-cost[idx] * c1) - 1.0f;
    const short eb = (short)f2bf(e);
    EB[swzw(j, i)] = eb;
    EA[swzw(i, j)] = eb;
  }
  __syncthreads();

  const int row0 = (blockIdx.x << 6) + (wv << 4);  // 16 rows per wave

  // ---- logs of inputs, directly in the MFMA D layouts (row = cl, comp = 16mt+4h+q)
  f32x4 l2a[8], l2b[8];
#pragma unroll
  for (int mt = 0; mt < 8; ++mt) {
    const int rr = (row0 + cl) << 7;
    const float4 va = *reinterpret_cast<const float4*>(&pred[rr + (mt << 4) + (h << 2)]);
    const float4 vb = *reinterpret_cast<const float4*>(&tgt [rr + (mt << 4) + (h << 2)]);
    f32x4 ta, tb;
    ta[0] = __builtin_amdgcn_logf(va.x + EPSF); ta[1] = __builtin_amdgcn_logf(va.y + EPSF);
    ta[2] = __builtin_amdgcn_logf(va.z + EPSF); ta[3] = __builtin_amdgcn_logf(va.w + EPSF);
    tb[0] = __builtin_amdgcn_logf(vb.x + EPSF); tb[1] = __builtin_amdgcn_logf(vb.y + EPSF);
    tb[2] = __builtin_amdgcn_logf(vb.z + EPSF); tb[3] = __builtin_amdgcn_logf(vb.w + EPSF);
    l2a[mt] = ta;
    l2b[mt] = tb;
  }

  // ---- state
  s16x8 uf[4], vf[4];
  {
    s16x8 ones;
#pragma unroll
    for (int k = 0; k < 8; ++k) ones[k] = (short)0x3F80;  // bf16 1.0
#pragma unroll
    for (int s = 0; s < 4; ++s) uf[s] = ones;
  }
  float sum_u = 128.0f;
  float m2u   = -7.0f;   // log2(1/128)
  float m2v, sum_v;
  f32x4 X[8];

  for (int it = 0; it < NITER; ++it) {
    // ======== MV1: X = E^T x U^T  (then Sv = sum_u + X) ========
#pragma unroll
    for (int mt = 0; mt < 8; ++mt) X[mt] = f32x4{0, 0, 0, 0};
#pragma unroll
    for (int s = 0; s < 4; ++s)
#pragma unroll
      for (int mt = 0; mt < 8; ++mt) {
        const s16x8 a = afrag(EA, cl + (mt << 4), s << 5, h);
        X[mt] = __builtin_amdgcn_mfma_f32_16x16x32_bf16(a, uf[s], X[mt], 0, 0, 0);
      }
    // stage1 finish: l2v = l2b - log2(Sv) - m2u ; m2v ; v = 2^(l2v-m2v) ; sum_v
    {
      float m = -3.0e38f;
#pragma unroll
      for (int mt = 0; mt < 8; ++mt)
#pragma unroll
        for (int q = 0; q < 4; ++q) {
          const float lv = l2b[mt][q]
                         - __builtin_amdgcn_logf(sum_u + X[mt][q])
                         - m2u;
          X[mt][q] = lv;
          m = fmaxf(m, lv);
        }
      m = fmaxf(m, __shfl_xor(m, 16));
      m = fmaxf(m, __shfl_xor(m, 32));
      m2v = m;
      float sv = 0.f;
#pragma unroll
      for (int mt = 0; mt < 8; ++mt)
#pragma unroll
        for (int q = 0; q < 4; ++q) {
          const float v = __builtin_amdgcn_exp2f(X[mt][q] - m);
          X[mt][q] = v;
          sv += v;
        }
      sv += __shfl_xor(sv, 16);
      sv += __shfl_xor(sv, 32);
      sum_v = sv;
    }
#pragma unroll
    for (int s = 0; s < 4; ++s) vf[s] = packb(X[2 * s], X[2 * s + 1]);

    // ======== MV2: X = E x V^T  (then Su = sum_v + X) ========
#pragma unroll
    for (int mt = 0; mt < 8; ++mt) X[mt] = f32x4{0, 0, 0, 0};
#pragma unroll
    for (int s = 0; s < 4; ++s)
#pragma unroll
      for (int mt = 0; mt < 8; ++mt) {
        const s16x8 a = afrag(EB, cl + (mt << 4), s << 5, h);
        X[mt] = __builtin_amdgcn_mfma_f32_16x16x32_bf16(a, vf[s], X[mt], 0, 0, 0);
      }
    // stage2 finish: l2u = l2a - log2(Su + EPS) - m2v ; m2u
    {
      float m = -3.0e38f;
#pragma unroll
      for (int mt = 0; mt < 8; ++mt)
#pragma unroll
        for (int q = 0; q < 4; ++q) {
          const float lu = l2a[mt][q]
                         - __builtin_amdgcn_logf(sum_v + X[mt][q] + EPSF)
                         - m2v;
          X[mt][q] = lu;
          m = fmaxf(m, lu);
        }
      m = fmaxf(m, __shfl_xor(m, 16));
      m = fmaxf(m, __shfl_xor(m, 32));
      m2u = m;
    }
    if (it < NITER - 1) {
      float su = 0.f;
#pragma unroll
      for (int s = 0; s < 4; ++s) {
        f32x4 ua, ub;
#pragma unroll
        for (int q = 0; q < 4; ++q) {
          ua[q] = __builtin_amdgcn_exp2f(X[2 * s][q] - m2u);
          su += ua[q];
        }
#pragma unroll
        for (int q = 0; q < 4; ++q) {
          ub[q] = __builtin_amdgcn_exp2f(X[2 * s + 1][q] - m2u);
          su += ub[q];
        }
        uf[s] = packb(ua, ub);
      }
      su += __shfl_xor(su, 16);
      su += __shfl_xor(su, 32);
      sum_u = su;
    }
  }

  // ======== final: T = KM x V^T with KM = hi + lo bf16 split ========
  __syncthreads();
  for (int idx = tid; idx < 128 * 128; idx += 256) {
    const int j = idx >> 7, i = idx & 127;
    const float cst = cost[idx];
    const float km  = cst * __builtin_amdgcn_exp2f(-cst * c1);
    const unsigned short khi = f2bf(km);
    const unsigned short klo = f2bf(km - bf2f(khi));
    const int w = swzw(j, i);
    EB[w] = (short)khi;
    EA[w] = (short)klo;
  }
  __syncthreads();

  f32x4 T[8];
#pragma unroll
  for (int mt = 0; mt < 8; ++mt) T[mt] = f32x4{0, 0, 0, 0};
#pragma unroll
  for (int s = 0; s < 4; ++s)
#pragma unroll
    for (int mt = 0; mt < 8; ++mt) {
      const s16x8 ahi = afrag(EB, cl + (mt << 4), s << 5, h);
      const s16x8 alo = afrag(EA, cl + (mt << 4), s << 5, h);
      T[mt] = __builtin_amdgcn_mfma_f32_16x16x32_bf16(ahi, vf[s], T[mt], 0, 0, 0);
      T[mt] = __builtin_amdgcn_mfma_f32_16x16x32_bf16(alo, vf[s], T[mt], 0, 0, 0);
    }

  // wnorm partial: sum 2^(l2u + log2(T+EPS) + m2v)
  float wsum = 0.f;
#pragma unroll
  for (int mt = 0; mt < 8; ++mt)
#pragma unroll
    for (int q = 0; q < 4; ++q)
      wsum += __builtin_amdgcn_exp2f(X[mt][q]
                + __builtin_amdgcn_logf(T[mt][q] + EPSF) + m2v);
  wsum += __shfl_xor(wsum, 1);
  wsum += __shfl_xor(wsum, 2);
  wsum += __shfl_xor(wsum, 4);
  wsum += __shfl_xor(wsum, 8);
  wsum += __shfl_xor(wsum, 16);
  wsum += __shfl_xor(wsum, 32);
  if (lane == 0) wred[wv] = wsum;

  // grad = (l2u - rowmean) * ln2 * lam / B
  {
    float sm = 0.f;
#pragma unroll
    for (int mt = 0; mt < 8; ++mt)
#pragma unroll
      for (int q = 0; q < 4; ++q) sm += X[mt][q];
    sm += __shfl_xor(sm, 16);
    sm += __shfl_xor(sm, 32);
    const float mean = sm * 0.0078125f;
    const int rr = 1 + ((row0 + cl) << 7) + (h << 2);
#pragma unroll
    for (int mt = 0; mt < 8; ++mt)
#pragma unroll
      for (int q = 0; q < 4; ++q)
        out[rr + (mt << 4) + q] = (X[mt][q] - mean) * GRADS;
  }

  __syncthreads();
  if (tid == 0) ws[blockIdx.x] = wred[0] + wred[1] + wred[2] + wred[3];
}

__global__ void sink_reduce(const float* __restrict__ ws, float* __restrict__ out)
{
  float s = 0.f;
  for (int i = threadIdx.x; i < 1024; i += 256) s += ws[i];
  s += __shfl_xor(s, 1);
  s += __shfl_xor(s, 2);
  s += __shfl_xor(s, 4);
  s += __shfl_xor(s, 8);
  s += __shfl_xor(s, 16);
  s += __shfl_xor(s, 32);
  __shared__ float sm[4];
  if ((threadIdx.x & 63) == 0) sm[threadIdx.x >> 6] = s;
  __syncthreads();
  if (threadIdx.x == 0) out[0] = (sm[0] + sm[1] + sm[2] + sm[3]) * (1.0f / 65536.0f);
}

extern "C" void kernel_launch(void* const* d_in, const int* in_sizes, int n_in,
                              void* d_out, int out_size, void* d_ws, size_t ws_size,
                              hipStream_t stream)
{
  const float* pred = (const float*)d_in[0];
  const float* tgt  = (const float*)d_in[1];
  const float* cost = (const float*)d_in[2];
  float* out = (float*)d_out;
  float* ws  = (float*)d_ws;

  sink_mfma<<<1024, 256, 0, stream>>>(pred, tgt, cost, out, ws);
  sink_reduce<<<1, 256, 0, stream>>>(ws, out);
}

// Round 4
// 256.461 us; speedup vs baseline: 4.1890x; 1.6024x over previous
//
#include <hip/hip_runtime.h>

// Sinkhorn via MFMA, normalization-free inner loop.
// K = exp(-cost/100) = 1 + E, |E| <= 0.00995; u@K = sum(u) + u@E (bf16 MFMA
// carries only the 0.5% correction -> fp32-class accuracy).
// Key algebra: v_stab = (b/Sv)/max(b/Sv), u_stab = (a/(Su+eps))/max(..);
// the running log-maxes cancel in BOTH outputs (grad is row-centered; wnorm
// term = ru*(T+eps)), so the loop is pure {mfma, rcp, mul, add, wave-reduce}
// -- no logs/exps, and no spilled log-state (round 3 spilled ~850MB to HBM).
// Logs appear once, in the grad epilogue. a+eps, b+eps held as bf16 (CLT:
// 8.4M independent RNE roundings -> ~2e-5 wnorm error, 3e-6 grad error).
// 6 iterations: Hilbert contraction ~2.5e-5/iter, fp32 fixed point by iter 3.

typedef __attribute__((ext_vector_type(4))) float f32x4;
typedef __attribute__((ext_vector_type(4))) short s16x4;
typedef __attribute__((ext_vector_type(8))) short s16x8;

constexpr int   NITER = 6;
constexpr float EPSF  = 1e-8f;
constexpr float LOG2E = 1.44269504088896340736f;
constexpr float LN2   = 0.69314718055994530942f;
constexpr float GRADS = LN2 * 100.0f / 65536.0f;   // ln2 * lam / B

__device__ __forceinline__ unsigned short f2bf(float x) {
  unsigned u = __builtin_bit_cast(unsigned, x);
  u += 0x7fffu + ((u >> 16) & 1u);
  return (unsigned short)(u >> 16);
}
__device__ __forceinline__ float bf2f(short h) {
  return __builtin_bit_cast(float, (unsigned)(unsigned short)h << 16);
}

// word index of element (r,c) of a 128x128 bf16 matrix, row-major, with a
// granule(8B)-XOR swizzle keyed on row bits 0..2 -> A-frag reads conflict-free.
__device__ __forceinline__ int swzw(int r, int c) {
  return (r << 7) + ((((c >> 2) ^ ((r & 7) << 2)) << 2) | (c & 3));
}

// A-fragment (16x16x32 bf16), k-permuted to match the chained D->B layout.
__device__ __forceinline__ s16x8 afrag(const short* M, int row, int kb, int h) {
  const int base = (row << 7) + ((((kb >> 2) + h) ^ ((row & 7) << 2)) << 2);
  const s16x4 lo = *reinterpret_cast<const s16x4*>(M + base);
  const s16x4 hi = *reinterpret_cast<const s16x4*>(M + (base ^ 16));
  s16x8 r;
  r[0] = lo[0]; r[1] = lo[1]; r[2] = lo[2]; r[3] = lo[3];
  r[4] = hi[0]; r[5] = hi[1]; r[6] = hi[2]; r[7] = hi[3];
  return r;
}

__device__ __forceinline__ s16x8 packb(const f32x4 a, const f32x4 b) {
  s16x8 r;
  r[0] = (short)f2bf(a[0]); r[1] = (short)f2bf(a[1]);
  r[2] = (short)f2bf(a[2]); r[3] = (short)f2bf(a[3]);
  r[4] = (short)f2bf(b[0]); r[5] = (short)f2bf(b[1]);
  r[6] = (short)f2bf(b[2]); r[7] = (short)f2bf(b[3]);
  return r;
}

__global__ __launch_bounds__(256, 2)
void sink_mfma(const float* __restrict__ pred,
               const float* __restrict__ tgt,
               const float* __restrict__ cost,
               float* __restrict__ out,
               float* __restrict__ ws)
{
  __shared__ __align__(16) short EA[128 * 128]; // E^T (MV1 A operand)
  __shared__ __align__(16) short EB[128 * 128]; // E   (MV2 A operand)
  __shared__ float wred[4];

  const int tid  = threadIdx.x;
  const int lane = tid & 63;
  const int wv   = tid >> 6;
  const int cl   = lane & 15;
  const int h    = lane >> 4;
  const float c1 = LOG2E * 0.01f;  // K = 2^(-cost*c1)

  // ---- stage E = K - 1 (bf16) into both LDS layouts
  for (int idx = tid; idx < 128 * 128; idx += 256) {
    const int j = idx >> 7, i = idx & 127;
    const float e = __builtin_amdgcn_exp2f(-cost[idx] * c1) - 1.0f;
    const short eb = (short)f2bf(e);
    EB[swzw(j, i)] = eb;
    EA[swzw(i, j)] = eb;
  }
  __syncthreads();

  const int row0 = (blockIdx.x << 6) + (wv << 4);  // 16 batch rows per wave
  const int rr   = (row0 + cl) << 7;

  // ---- a+eps, b+eps as bf16 in the MFMA D layout (elem (mt,q) -> [mt>>1][(mt&1)*4+q])
  s16x8 ab[4], bb[4];
#pragma unroll
  for (int s = 0; s < 4; ++s) {
    const float4 p0 = *reinterpret_cast<const float4*>(&pred[rr + ((2 * s) << 4) + (h << 2)]);
    const float4 p1 = *reinterpret_cast<const float4*>(&pred[rr + ((2 * s + 1) << 4) + (h << 2)]);
    const float4 t0 = *reinterpret_cast<const float4*>(&tgt [rr + ((2 * s) << 4) + (h << 2)]);
    const float4 t1 = *reinterpret_cast<const float4*>(&tgt [rr + ((2 * s + 1) << 4) + (h << 2)]);
    f32x4 qa0, qa1, qb0, qb1;
    qa0[0] = p0.x + EPSF; qa0[1] = p0.y + EPSF; qa0[2] = p0.z + EPSF; qa0[3] = p0.w + EPSF;
    qa1[0] = p1.x + EPSF; qa1[1] = p1.y + EPSF; qa1[2] = p1.z + EPSF; qa1[3] = p1.w + EPSF;
    qb0[0] = t0.x + EPSF; qb0[1] = t0.y + EPSF; qb0[2] = t0.z + EPSF; qb0[3] = t0.w + EPSF;
    qb1[0] = t1.x + EPSF; qb1[1] = t1.y + EPSF; qb1[2] = t1.z + EPSF; qb1[3] = t1.w + EPSF;
    ab[s] = packb(qa0, qa1);
    bb[s] = packb(qb0, qb1);
  }

  // ---- state: u fragments (bf16), wave-uniform row sums
  s16x8 uf[4], vf[4];
  {
    s16x8 ones;
#pragma unroll
    for (int k = 0; k < 8; ++k) ones[k] = (short)0x3F80;  // bf16 1.0
#pragma unroll
    for (int s = 0; s < 4; ++s) uf[s] = ones;
  }
  float sum_u = 128.0f;
  float sum_v = 0.0f;
  f32x4 X[8];

  for (int it = 0; it < NITER; ++it) {
    // ======== MV1: X = E^T x U^T ; Sv = sum_u + X ; r = b/Sv ========
#pragma unroll
    for (int mt = 0; mt < 8; ++mt) X[mt] = f32x4{0, 0, 0, 0};
#pragma unroll
    for (int s = 0; s < 4; ++s)
#pragma unroll
      for (int mt = 0; mt < 8; ++mt) {
        const s16x8 a = afrag(EA, cl + (mt << 4), s << 5, h);
        X[mt] = __builtin_amdgcn_mfma_f32_16x16x32_bf16(a, uf[s], X[mt], 0, 0, 0);
      }
    float rmx = 0.f;
#pragma unroll
    for (int mt = 0; mt < 8; ++mt)
#pragma unroll
      for (int q = 0; q < 4; ++q) {
        const float r = bf2f(bb[mt >> 1][(mt & 1) * 4 + q]) *
                        __builtin_amdgcn_rcpf(sum_u + X[mt][q]);
        X[mt][q] = r;
        rmx = fmaxf(rmx, r);
      }
    rmx = fmaxf(rmx, __shfl_xor(rmx, 16));
    rmx = fmaxf(rmx, __shfl_xor(rmx, 32));
    const float inv = __builtin_amdgcn_rcpf(rmx);
    float sr = 0.f;
#pragma unroll
    for (int mt = 0; mt < 8; ++mt)
#pragma unroll
      for (int q = 0; q < 4; ++q) sr += X[mt][q];
#pragma unroll
    for (int s = 0; s < 4; ++s) {
      f32x4 v0, v1;
#pragma unroll
      for (int q = 0; q < 4; ++q) { v0[q] = X[2 * s][q] * inv; v1[q] = X[2 * s + 1][q] * inv; }
      vf[s] = packb(v0, v1);
    }
    sr += __shfl_xor(sr, 16);
    sr += __shfl_xor(sr, 32);
    sum_v = sr * inv;

    // ======== MV2: X = E x V^T ; Su = sum_v + X + eps ; ru = a/Su ========
#pragma unroll
    for (int mt = 0; mt < 8; ++mt) X[mt] = f32x4{0, 0, 0, 0};
#pragma unroll
    for (int s = 0; s < 4; ++s)
#pragma unroll
      for (int mt = 0; mt < 8; ++mt) {
        const s16x8 a = afrag(EB, cl + (mt << 4), s << 5, h);
        X[mt] = __builtin_amdgcn_mfma_f32_16x16x32_bf16(a, vf[s], X[mt], 0, 0, 0);
      }
#pragma unroll
    for (int mt = 0; mt < 8; ++mt)
#pragma unroll
      for (int q = 0; q < 4; ++q)
        X[mt][q] = bf2f(ab[mt >> 1][(mt & 1) * 4 + q]) *
                   __builtin_amdgcn_rcpf(sum_v + X[mt][q] + EPSF);   // ru

    if (it < NITER - 1) {
      float rmu = 0.f;
#pragma unroll
      for (int mt = 0; mt < 8; ++mt)
#pragma unroll
        for (int q = 0; q < 4; ++q) rmu = fmaxf(rmu, X[mt][q]);
      rmu = fmaxf(rmu, __shfl_xor(rmu, 16));
      rmu = fmaxf(rmu, __shfl_xor(rmu, 32));
      const float inv2 = __builtin_amdgcn_rcpf(rmu);
      float su = 0.f;
#pragma unroll
      for (int mt = 0; mt < 8; ++mt)
#pragma unroll
        for (int q = 0; q < 4; ++q) su += X[mt][q];
#pragma unroll
      for (int s = 0; s < 4; ++s) {
        f32x4 u0, u1;
#pragma unroll
        for (int q = 0; q < 4; ++q) { u0[q] = X[2 * s][q] * inv2; u1[q] = X[2 * s + 1][q] * inv2; }
        uf[s] = packb(u0, u1);
      }
      su += __shfl_xor(su, 16);
      su += __shfl_xor(su, 32);
      sum_u = su * inv2;
    }
  }
  // X now holds final ru ; vf holds final v_stab ; wnorm term = ru*(T+eps).

  // ======== final: T = KM x V^T with KM = hi + lo bf16 split ========
  __syncthreads();
  for (int idx = tid; idx < 128 * 128; idx += 256) {
    const int j = idx >> 7, i = idx & 127;
    const float cst = cost[idx];
    const float km  = cst * __builtin_amdgcn_exp2f(-cst * c1);
    const unsigned short khi = f2bf(km);
    const unsigned short klo = f2bf(km - bf2f((short)khi));
    const int w = swzw(j, i);
    EB[w] = (short)khi;
    EA[w] = (short)klo;
  }
  __syncthreads();

  f32x4 T[8];
#pragma unroll
  for (int mt = 0; mt < 8; ++mt) T[mt] = f32x4{0, 0, 0, 0};
#pragma unroll
  for (int s = 0; s < 4; ++s)
#pragma unroll
    for (int mt = 0; mt < 8; ++mt) {
      const s16x8 ahi = afrag(EB, cl + (mt << 4), s << 5, h);
      const s16x8 alo = afrag(EA, cl + (mt << 4), s << 5, h);
      T[mt] = __builtin_amdgcn_mfma_f32_16x16x32_bf16(ahi, vf[s], T[mt], 0, 0, 0);
      T[mt] = __builtin_amdgcn_mfma_f32_16x16x32_bf16(alo, vf[s], T[mt], 0, 0, 0);
    }

  // wnorm partial: sum ru*(T+eps)   (all stabilizers cancel exactly)
  float wsum = 0.f;
#pragma unroll
  for (int mt = 0; mt < 8; ++mt)
#pragma unroll
    for (int q = 0; q < 4; ++q)
      wsum += X[mt][q] * (T[mt][q] + EPSF);
  wsum += __shfl_xor(wsum, 1);
  wsum += __shfl_xor(wsum, 2);
  wsum += __shfl_xor(wsum, 4);
  wsum += __shfl_xor(wsum, 8);
  wsum += __shfl_xor(wsum, 16);
  wsum += __shfl_xor(wsum, 32);
  if (lane == 0) wred[wv] = wsum;

  // grad = (log2(ru) - rowmean(log2(ru))) * ln2 * lam / B  (m_v cancels)
  {
#pragma unroll
    for (int mt = 0; mt < 8; ++mt)
#pragma unroll
      for (int q = 0; q < 4; ++q)
        X[mt][q] = __builtin_amdgcn_logf(X[mt][q]);
    float sm = 0.f;
#pragma unroll
    for (int mt = 0; mt < 8; ++mt)
#pragma unroll
      for (int q = 0; q < 4; ++q) sm += X[mt][q];
    sm += __shfl_xor(sm, 16);
    sm += __shfl_xor(sm, 32);
    const float mean = sm * 0.0078125f;
    const int ro = 1 + rr + (h << 2);
#pragma unroll
    for (int mt = 0; mt < 8; ++mt)
#pragma unroll
      for (int q = 0; q < 4; ++q)
        out[ro + (mt << 4) + q] = (X[mt][q] - mean) * GRADS;
  }

  __syncthreads();
  if (tid == 0) ws[blockIdx.x] = wred[0] + wred[1] + wred[2] + wred[3];
}

__global__ void sink_reduce(const float* __restrict__ ws, float* __restrict__ out)
{
  float s = 0.f;
  for (int i = threadIdx.x; i < 1024; i += 256) s += ws[i];
  s += __shfl_xor(s, 1);
  s += __shfl_xor(s, 2);
  s += __shfl_xor(s, 4);
  s += __shfl_xor(s, 8);
  s += __shfl_xor(s, 16);
  s += __shfl_xor(s, 32);
  __shared__ float sm[4];
  if ((threadIdx.x & 63) == 0) sm[threadIdx.x >> 6] = s;
  __syncthreads();
  if (threadIdx.x == 0) out[0] = (sm[0] + sm[1] + sm[2] + sm[3]) * (1.0f / 65536.0f);
}

extern "C" void kernel_launch(void* const* d_in, const int* in_sizes, int n_in,
                              void* d_out, int out_size, void* d_ws, size_t ws_size,
                              hipStream_t stream)
{
  const float* pred = (const float*)d_in[0];
  const float* tgt  = (const float*)d_in[1];
  const float* cost = (const float*)d_in[2];
  float* out = (float*)d_out;
  float* ws  = (float*)d_ws;

  sink_mfma<<<1024, 256, 0, stream>>>(pred, tgt, cost, out, ws);
  sink_reduce<<<1, 256, 0, stream>>>(ws, out);
}

// Round 5
// 256.033 us; speedup vs baseline: 4.1961x; 1.0017x over previous
//
#include <hip/hip_runtime.h>

// Sinkhorn via MFMA, normalization-free inner loop.
// K = exp(-cost/100) = 1 + E, |E| <= 0.00995; u@K = sum(u) + u@E (bf16 MFMA
// carries only the 0.5% correction -> fp32-class accuracy).
// v_stab = (b/Sv)/max(b/Sv), u_stab = (a/(Su+eps))/max(..); the running
// log-maxes cancel in BOTH outputs, so the loop is pure {mfma, rcp, mul, add,
// wave-reduce}. Logs appear once, in the grad epilogue.
//
// Round-5 change: rounds 2-4 all spilled (VGPR_Count pinned at 128 = 4 waves/
// EU reg target while LDS caps us at 2 blocks/CU anyway). Declare
// amdgpu_waves_per_eu(2) -> 256-VGPR budget, zero scratch. Inner MFMA loops
// chunked per s (load 8 frags, fire 8 MFMAs) to keep the hoist window small.

typedef __attribute__((ext_vector_type(4))) float f32x4;
typedef __attribute__((ext_vector_type(4))) short s16x4;
typedef __attribute__((ext_vector_type(8))) short s16x8;

constexpr int   NITER = 6;
constexpr float EPSF  = 1e-8f;
constexpr float LOG2E = 1.44269504088896340736f;
constexpr float LN2   = 0.69314718055994530942f;
constexpr float GRADS = LN2 * 100.0f / 65536.0f;   // ln2 * lam / B

__device__ __forceinline__ unsigned short f2bf(float x) {
  unsigned u = __builtin_bit_cast(unsigned, x);
  u += 0x7fffu + ((u >> 16) & 1u);
  return (unsigned short)(u >> 16);
}
__device__ __forceinline__ float bf2f(short h) {
  return __builtin_bit_cast(float, (unsigned)(unsigned short)h << 16);
}

// word index of element (r,c) of a 128x128 bf16 matrix, row-major, with a
// granule(8B)-XOR swizzle keyed on row bits 0..2 -> A-frag reads conflict-free.
__device__ __forceinline__ int swzw(int r, int c) {
  return (r << 7) + ((((c >> 2) ^ ((r & 7) << 2)) << 2) | (c & 3));
}

// A-fragment (16x16x32 bf16), k-permuted to match the chained D->B layout.
__device__ __forceinline__ s16x8 afrag(const short* M, int row, int kb, int h) {
  const int base = (row << 7) + ((((kb >> 2) + h) ^ ((row & 7) << 2)) << 2);
  const s16x4 lo = *reinterpret_cast<const s16x4*>(M + base);
  const s16x4 hi = *reinterpret_cast<const s16x4*>(M + (base ^ 16));
  s16x8 r;
  r[0] = lo[0]; r[1] = lo[1]; r[2] = lo[2]; r[3] = lo[3];
  r[4] = hi[0]; r[5] = hi[1]; r[6] = hi[2]; r[7] = hi[3];
  return r;
}

__device__ __forceinline__ s16x8 packb(const f32x4 a, const f32x4 b) {
  s16x8 r;
  r[0] = (short)f2bf(a[0]); r[1] = (short)f2bf(a[1]);
  r[2] = (short)f2bf(a[2]); r[3] = (short)f2bf(a[3]);
  r[4] = (short)f2bf(b[0]); r[5] = (short)f2bf(b[1]);
  r[6] = (short)f2bf(b[2]); r[7] = (short)f2bf(b[3]);
  return r;
}

__global__ __launch_bounds__(256)
__attribute__((amdgpu_waves_per_eu(2)))
void sink_mfma(const float* __restrict__ pred,
               const float* __restrict__ tgt,
               const float* __restrict__ cost,
               float* __restrict__ out,
               float* __restrict__ ws)
{
  __shared__ __align__(16) short EA[128 * 128]; // E^T (MV1 A operand)
  __shared__ __align__(16) short EB[128 * 128]; // E   (MV2 A operand)
  __shared__ float wred[4];

  const int tid  = threadIdx.x;
  const int lane = tid & 63;
  const int wv   = tid >> 6;
  const int cl   = lane & 15;
  const int h    = lane >> 4;
  const float c1 = LOG2E * 0.01f;  // K = 2^(-cost*c1)

  // ---- stage E = K - 1 (bf16) into both LDS layouts
  for (int idx = tid; idx < 128 * 128; idx += 256) {
    const int j = idx >> 7, i = idx & 127;
    const float e = __builtin_amdgcn_exp2f(-cost[idx] * c1) - 1.0f;
    const short eb = (short)f2bf(e);
    EB[swzw(j, i)] = eb;
    EA[swzw(i, j)] = eb;
  }
  __syncthreads();

  const int row0 = (blockIdx.x << 6) + (wv << 4);  // 16 batch rows per wave
  const int rr   = (row0 + cl) << 7;

  // ---- a+eps, b+eps as bf16 in the MFMA D layout (elem (mt,q) -> [mt>>1][(mt&1)*4+q])
  s16x8 ab[4], bb[4];
#pragma unroll
  for (int s = 0; s < 4; ++s) {
    const float4 p0 = *reinterpret_cast<const float4*>(&pred[rr + ((2 * s) << 4) + (h << 2)]);
    const float4 p1 = *reinterpret_cast<const float4*>(&pred[rr + ((2 * s + 1) << 4) + (h << 2)]);
    const float4 t0 = *reinterpret_cast<const float4*>(&tgt [rr + ((2 * s) << 4) + (h << 2)]);
    const float4 t1 = *reinterpret_cast<const float4*>(&tgt [rr + ((2 * s + 1) << 4) + (h << 2)]);
    f32x4 qa0, qa1, qb0, qb1;
    qa0[0] = p0.x + EPSF; qa0[1] = p0.y + EPSF; qa0[2] = p0.z + EPSF; qa0[3] = p0.w + EPSF;
    qa1[0] = p1.x + EPSF; qa1[1] = p1.y + EPSF; qa1[2] = p1.z + EPSF; qa1[3] = p1.w + EPSF;
    qb0[0] = t0.x + EPSF; qb0[1] = t0.y + EPSF; qb0[2] = t0.z + EPSF; qb0[3] = t0.w + EPSF;
    qb1[0] = t1.x + EPSF; qb1[1] = t1.y + EPSF; qb1[2] = t1.z + EPSF; qb1[3] = t1.w + EPSF;
    ab[s] = packb(qa0, qa1);
    bb[s] = packb(qb0, qb1);
  }

  // ---- state: u fragments (bf16), wave-uniform row sums
  s16x8 uf[4], vf[4];
  {
    s16x8 ones;
#pragma unroll
    for (int k = 0; k < 8; ++k) ones[k] = (short)0x3F80;  // bf16 1.0
#pragma unroll
    for (int s = 0; s < 4; ++s) uf[s] = ones;
  }
  float sum_u = 128.0f;
  float sum_v = 0.0f;
  f32x4 X[8];

  for (int it = 0; it < NITER; ++it) {
    // ======== MV1: X = E^T x U^T ; Sv = sum_u + X ; r = b/Sv ========
#pragma unroll
    for (int mt = 0; mt < 8; ++mt) X[mt] = f32x4{0, 0, 0, 0};
#pragma unroll
    for (int s = 0; s < 4; ++s) {
      s16x8 fr[8];
#pragma unroll
      for (int mt = 0; mt < 8; ++mt) fr[mt] = afrag(EA, cl + (mt << 4), s << 5, h);
#pragma unroll
      for (int mt = 0; mt < 8; ++mt)
        X[mt] = __builtin_amdgcn_mfma_f32_16x16x32_bf16(fr[mt], uf[s], X[mt], 0, 0, 0);
    }
    float rmx = 0.f;
#pragma unroll
    for (int mt = 0; mt < 8; ++mt)
#pragma unroll
      for (int q = 0; q < 4; ++q) {
        const float r = bf2f(bb[mt >> 1][(mt & 1) * 4 + q]) *
                        __builtin_amdgcn_rcpf(sum_u + X[mt][q]);
        X[mt][q] = r;
        rmx = fmaxf(rmx, r);
      }
    rmx = fmaxf(rmx, __shfl_xor(rmx, 16));
    rmx = fmaxf(rmx, __shfl_xor(rmx, 32));
    const float inv = __builtin_amdgcn_rcpf(rmx);
    float sr = 0.f;
#pragma unroll
    for (int mt = 0; mt < 8; ++mt)
#pragma unroll
      for (int q = 0; q < 4; ++q) sr += X[mt][q];
#pragma unroll
    for (int s = 0; s < 4; ++s) {
      f32x4 v0, v1;
#pragma unroll
      for (int q = 0; q < 4; ++q) { v0[q] = X[2 * s][q] * inv; v1[q] = X[2 * s + 1][q] * inv; }
      vf[s] = packb(v0, v1);
    }
    sr += __shfl_xor(sr, 16);
    sr += __shfl_xor(sr, 32);
    sum_v = sr * inv;

    // ======== MV2: X = E x V^T ; Su = sum_v + X + eps ; ru = a/Su ========
#pragma unroll
    for (int mt = 0; mt < 8; ++mt) X[mt] = f32x4{0, 0, 0, 0};
#pragma unroll
    for (int s = 0; s < 4; ++s) {
      s16x8 fr[8];
#pragma unroll
      for (int mt = 0; mt < 8; ++mt) fr[mt] = afrag(EB, cl + (mt << 4), s << 5, h);
#pragma unroll
      for (int mt = 0; mt < 8; ++mt)
        X[mt] = __builtin_amdgcn_mfma_f32_16x16x32_bf16(fr[mt], vf[s], X[mt], 0, 0, 0);
    }
#pragma unroll
    for (int mt = 0; mt < 8; ++mt)
#pragma unroll
      for (int q = 0; q < 4; ++q)
        X[mt][q] = bf2f(ab[mt >> 1][(mt & 1) * 4 + q]) *
                   __builtin_amdgcn_rcpf(sum_v + X[mt][q] + EPSF);   // ru

    if (it < NITER - 1) {
      float rmu = 0.f;
#pragma unroll
      for (int mt = 0; mt < 8; ++mt)
#pragma unroll
        for (int q = 0; q < 4; ++q) rmu = fmaxf(rmu, X[mt][q]);
      rmu = fmaxf(rmu, __shfl_xor(rmu, 16));
      rmu = fmaxf(rmu, __shfl_xor(rmu, 32));
      const float inv2 = __builtin_amdgcn_rcpf(rmu);
      float su = 0.f;
#pragma unroll
      for (int mt = 0; mt < 8; ++mt)
#pragma unroll
        for (int q = 0; q < 4; ++q) su += X[mt][q];
#pragma unroll
      for (int s = 0; s < 4; ++s) {
        f32x4 u0, u1;
#pragma unroll
        for (int q = 0; q < 4; ++q) { u0[q] = X[2 * s][q] * inv2; u1[q] = X[2 * s + 1][q] * inv2; }
        uf[s] = packb(u0, u1);
      }
      su += __shfl_xor(su, 16);
      su += __shfl_xor(su, 32);
      sum_u = su * inv2;
    }
  }
  // X now holds final ru ; vf holds final v_stab ; wnorm term = ru*(T+eps).

  // ======== final: T = KM x V^T with KM = hi + lo bf16 split ========
  __syncthreads();
  for (int idx = tid; idx < 128 * 128; idx += 256) {
    const int j = idx >> 7, i = idx & 127;
    const float cst = cost[idx];
    const float km  = cst * __builtin_amdgcn_exp2f(-cst * c1);
    const unsigned short khi = f2bf(km);
    const unsigned short klo = f2bf(km - bf2f((short)khi));
    const int w = swzw(j, i);
    EB[w] = (short)khi;
    EA[w] = (short)klo;
  }
  __syncthreads();

  f32x4 T[8];
#pragma unroll
  for (int mt = 0; mt < 8; ++mt) T[mt] = f32x4{0, 0, 0, 0};
#pragma unroll
  for (int s = 0; s < 4; ++s) {
    s16x8 fh[8], fl[8];
#pragma unroll
    for (int mt = 0; mt < 8; ++mt) {
      fh[mt] = afrag(EB, cl + (mt << 4), s << 5, h);
      fl[mt] = afrag(EA, cl + (mt << 4), s << 5, h);
    }
#pragma unroll
    for (int mt = 0; mt < 8; ++mt) {
      T[mt] = __builtin_amdgcn_mfma_f32_16x16x32_bf16(fh[mt], vf[s], T[mt], 0, 0, 0);
      T[mt] = __builtin_amdgcn_mfma_f32_16x16x32_bf16(fl[mt], vf[s], T[mt], 0, 0, 0);
    }
  }

  // wnorm partial: sum ru*(T+eps)   (all stabilizers cancel exactly)
  float wsum = 0.f;
#pragma unroll
  for (int mt = 0; mt < 8; ++mt)
#pragma unroll
    for (int q = 0; q < 4; ++q)
      wsum += X[mt][q] * (T[mt][q] + EPSF);
  wsum += __shfl_xor(wsum, 1);
  wsum += __shfl_xor(wsum, 2);
  wsum += __shfl_xor(wsum, 4);
  wsum += __shfl_xor(wsum, 8);
  wsum += __shfl_xor(wsum, 16);
  wsum += __shfl_xor(wsum, 32);
  if (lane == 0) wred[wv] = wsum;

  // grad = (log2(ru) - rowmean(log2(ru))) * ln2 * lam / B  (m_v cancels)
  {
#pragma unroll
    for (int mt = 0; mt < 8; ++mt)
#pragma unroll
      for (int q = 0; q < 4; ++q)
        X[mt][q] = __builtin_amdgcn_logf(X[mt][q]);
    float sm = 0.f;
#pragma unroll
    for (int mt = 0; mt < 8; ++mt)
#pragma unroll
      for (int q = 0; q < 4; ++q) sm += X[mt][q];
    sm += __shfl_xor(sm, 16);
    sm += __shfl_xor(sm, 32);
    const float mean = sm * 0.0078125f;
    const int ro = 1 + rr + (h << 2);
#pragma unroll
    for (int mt = 0; mt < 8; ++mt)
#pragma unroll
      for (int q = 0; q < 4; ++q)
        out[ro + (mt << 4) + q] = (X[mt][q] - mean) * GRADS;
  }

  __syncthreads();
  if (tid == 0) ws[blockIdx.x] = wred[0] + wred[1] + wred[2] + wred[3];
}

__global__ void sink_reduce(const float* __restrict__ ws, float* __restrict__ out)
{
  float s = 0.f;
  for (int i = threadIdx.x; i < 1024; i += 256) s += ws[i];
  s += __shfl_xor(s, 1);
  s += __shfl_xor(s, 2);
  s += __shfl_xor(s, 4);
  s += __shfl_xor(s, 8);
  s += __shfl_xor(s, 16);
  s += __shfl_xor(s, 32);
  __shared__ float sm[4];
  if ((threadIdx.x & 63) == 0) sm[threadIdx.x >> 6] = s;
  __syncthreads();
  if (threadIdx.x == 0) out[0] = (sm[0] + sm[1] + sm[2] + sm[3]) * (1.0f / 65536.0f);
}

extern "C" void kernel_launch(void* const* d_in, const int* in_sizes, int n_in,
                              void* d_out, int out_size, void* d_ws, size_t ws_size,
                              hipStream_t stream)
{
  const float* pred = (const float*)d_in[0];
  const float* tgt  = (const float*)d_in[1];
  const float* cost = (const float*)d_in[2];
  float* out = (float*)d_out;
  float* ws  = (float*)d_ws;

  sink_mfma<<<1024, 256, 0, stream>>>(pred, tgt, cost, out, ws);
  sink_reduce<<<1, 256, 0, stream>>>(ws, out);
}

// Round 6
// 249.090 us; speedup vs baseline: 4.3130x; 1.0279x over previous
//
#include <hip/hip_runtime.h>

// Sinkhorn via MFMA, normalization-free inner loop.
// K = exp(-cost/100) = 1 + E, |E| <= 0.00995; u@K = sum(u) + u@E (bf16 MFMA
// carries only the 0.5% correction -> fp32-class accuracy).
// v_stab = (b/Sv)/max(b/Sv), u_stab = (a/(Su+eps))/max(..); running maxes
// cancel in BOTH outputs -> loop is {mfma, rcp, mul, add, wave-reduce} only.
//
// Round-6 change: rounds 2-5 all re-fetched pred/tgt EVERY iteration
// (excess FETCH 415 MB == 262144 thr x 6 it x 256 B): with the 128-arch-VGPR
// partition the compiler rematerializes the input loads instead of keeping
// a,b live. Fix: a+eps, b+eps now live in LDS as packed bf16 pairs
// ([16][512] u32, bank = tid%32, conflict-free). 512-thread blocks, LDS =
// 64K (E,E^T) + 64K (a,b) = 128.5 KB -> 1 block/CU = 8 waves/CU (same
// occupancy as before), E-staging amortized over 2x rows.

typedef __attribute__((ext_vector_type(4))) float f32x4;
typedef __attribute__((ext_vector_type(4))) short s16x4;
typedef __attribute__((ext_vector_type(8))) short s16x8;

constexpr int   NITER = 6;
constexpr int   BLOCK = 512;               // 8 waves, 16 rows each
constexpr float EPSF  = 1e-8f;
constexpr float LOG2E = 1.44269504088896340736f;
constexpr float LN2   = 0.69314718055994530942f;
constexpr float GRADS = LN2 * 100.0f / 65536.0f;   // ln2 * lam / B

__device__ __forceinline__ unsigned short f2bf(float x) {
  unsigned u = __builtin_bit_cast(unsigned, x);
  u += 0x7fffu + ((u >> 16) & 1u);
  return (unsigned short)(u >> 16);
}
__device__ __forceinline__ float bf2f(short h) {
  return __builtin_bit_cast(float, (unsigned)(unsigned short)h << 16);
}
__device__ __forceinline__ unsigned pack2(float lo, float hi) {
  return (unsigned)f2bf(lo) | ((unsigned)f2bf(hi) << 16);
}

// word index of element (r,c) of a 128x128 bf16 matrix, row-major, with a
// granule(8B)-XOR swizzle keyed on row bits 0..2 -> A-frag reads conflict-free.
__device__ __forceinline__ int swzw(int r, int c) {
  return (r << 7) + ((((c >> 2) ^ ((r & 7) << 2)) << 2) | (c & 3));
}

// A-fragment (16x16x32 bf16), k-permuted to match the chained D->B layout.
__device__ __forceinline__ s16x8 afrag(const short* M, int row, int kb, int h) {
  const int base = (row << 7) + ((((kb >> 2) + h) ^ ((row & 7) << 2)) << 2);
  const s16x4 lo = *reinterpret_cast<const s16x4*>(M + base);
  const s16x4 hi = *reinterpret_cast<const s16x4*>(M + (base ^ 16));
  s16x8 r;
  r[0] = lo[0]; r[1] = lo[1]; r[2] = lo[2]; r[3] = lo[3];
  r[4] = hi[0]; r[5] = hi[1]; r[6] = hi[2]; r[7] = hi[3];
  return r;
}

__device__ __forceinline__ s16x8 packb(const f32x4 a, const f32x4 b) {
  s16x8 r;
  r[0] = (short)f2bf(a[0]); r[1] = (short)f2bf(a[1]);
  r[2] = (short)f2bf(a[2]); r[3] = (short)f2bf(a[3]);
  r[4] = (short)f2bf(b[0]); r[5] = (short)f2bf(b[1]);
  r[6] = (short)f2bf(b[2]); r[7] = (short)f2bf(b[3]);
  return r;
}

__global__ __launch_bounds__(BLOCK)
void sink_mfma(const float* __restrict__ pred,
               const float* __restrict__ tgt,
               const float* __restrict__ cost,
               float* __restrict__ out,
               float* __restrict__ ws)
{
  __shared__ __align__(16) short EA[128 * 128];   // E^T (MV1 A operand), 32KB
  __shared__ __align__(16) short EB[128 * 128];   // E   (MV2 A operand), 32KB
  __shared__ unsigned ABp[16 * BLOCK];            // a+eps bf16 pairs, 32KB
  __shared__ unsigned BBp[16 * BLOCK];            // b+eps bf16 pairs, 32KB
  __shared__ float wred[8];

  const int tid  = threadIdx.x;
  const int lane = tid & 63;
  const int wv   = tid >> 6;
  const int cl   = lane & 15;
  const int h    = lane >> 4;
  const float c1 = LOG2E * 0.01f;  // K = 2^(-cost*c1)

  // ---- stage E = K - 1 (bf16) into both LDS layouts
  for (int idx = tid; idx < 128 * 128; idx += BLOCK) {
    const int j = idx >> 7, i = idx & 127;
    const float e = __builtin_amdgcn_exp2f(-cost[idx] * c1) - 1.0f;
    const short eb = (short)f2bf(e);
    EB[swzw(j, i)] = eb;
    EA[swzw(i, j)] = eb;
  }

  const int row0 = (blockIdx.x << 7) + (wv << 4);  // 16 batch rows per wave
  const int rr   = (row0 + cl) << 7;

  // ---- a+eps, b+eps -> LDS as packed bf16 pairs.
  // elem e = mt*4+q lives at pair p = 2mt + (q>>1), half = q&1.
#pragma unroll
  for (int mt = 0; mt < 8; ++mt) {
    const float4 p4 = *reinterpret_cast<const float4*>(&pred[rr + (mt << 4) + (h << 2)]);
    const float4 t4 = *reinterpret_cast<const float4*>(&tgt [rr + (mt << 4) + (h << 2)]);
    ABp[((mt << 1) + 0) * BLOCK + tid] = pack2(p4.x + EPSF, p4.y + EPSF);
    ABp[((mt << 1) + 1) * BLOCK + tid] = pack2(p4.z + EPSF, p4.w + EPSF);
    BBp[((mt << 1) + 0) * BLOCK + tid] = pack2(t4.x + EPSF, t4.y + EPSF);
    BBp[((mt << 1) + 1) * BLOCK + tid] = pack2(t4.z + EPSF, t4.w + EPSF);
  }
  __syncthreads();

  // ---- state: u fragments (bf16), wave-uniform row sums
  s16x8 uf[4], vf[4];
  {
    s16x8 ones;
#pragma unroll
    for (int k = 0; k < 8; ++k) ones[k] = (short)0x3F80;  // bf16 1.0
#pragma unroll
    for (int s = 0; s < 4; ++s) uf[s] = ones;
  }
  float sum_u = 128.0f;
  float sum_v = 0.0f;
  f32x4 X[8];

  for (int it = 0; it < NITER; ++it) {
    // ======== MV1: X = E^T x U^T ; Sv = sum_u + X ; r = b/Sv ========
#pragma unroll
    for (int mt = 0; mt < 8; ++mt) X[mt] = f32x4{0, 0, 0, 0};
#pragma unroll
    for (int s = 0; s < 4; ++s) {
      s16x8 fr[8];
#pragma unroll
      for (int mt = 0; mt < 8; ++mt) fr[mt] = afrag(EA, cl + (mt << 4), s << 5, h);
#pragma unroll
      for (int mt = 0; mt < 8; ++mt)
        X[mt] = __builtin_amdgcn_mfma_f32_16x16x32_bf16(fr[mt], uf[s], X[mt], 0, 0, 0);
    }
    float rmx = 0.f;
#pragma unroll
    for (int mt = 0; mt < 8; ++mt)
#pragma unroll
      for (int k = 0; k < 2; ++k) {
        const unsigned u = BBp[((mt << 1) + k) * BLOCK + tid];
        const float b0 = __builtin_bit_cast(float, u << 16);
        const float b1 = __builtin_bit_cast(float, u & 0xFFFF0000u);
        const float r0 = b0 * __builtin_amdgcn_rcpf(sum_u + X[mt][2 * k]);
        const float r1 = b1 * __builtin_amdgcn_rcpf(sum_u + X[mt][2 * k + 1]);
        X[mt][2 * k]     = r0;
        X[mt][2 * k + 1] = r1;
        rmx = fmaxf(rmx, fmaxf(r0, r1));
      }
    rmx = fmaxf(rmx, __shfl_xor(rmx, 16));
    rmx = fmaxf(rmx, __shfl_xor(rmx, 32));
    const float inv = __builtin_amdgcn_rcpf(rmx);
    float sr = 0.f;
#pragma unroll
    for (int mt = 0; mt < 8; ++mt)
#pragma unroll
      for (int q = 0; q < 4; ++q) sr += X[mt][q];
#pragma unroll
    for (int s = 0; s < 4; ++s) {
      f32x4 v0, v1;
#pragma unroll
      for (int q = 0; q < 4; ++q) { v0[q] = X[2 * s][q] * inv; v1[q] = X[2 * s + 1][q] * inv; }
      vf[s] = packb(v0, v1);
    }
    sr += __shfl_xor(sr, 16);
    sr += __shfl_xor(sr, 32);
    sum_v = sr * inv;

    // ======== MV2: X = E x V^T ; Su = sum_v + X + eps ; ru = a/Su ========
#pragma unroll
    for (int mt = 0; mt < 8; ++mt) X[mt] = f32x4{0, 0, 0, 0};
#pragma unroll
    for (int s = 0; s < 4; ++s) {
      s16x8 fr[8];
#pragma unroll
      for (int mt = 0; mt < 8; ++mt) fr[mt] = afrag(EB, cl + (mt << 4), s << 5, h);
#pragma unroll
      for (int mt = 0; mt < 8; ++mt)
        X[mt] = __builtin_amdgcn_mfma_f32_16x16x32_bf16(fr[mt], vf[s], X[mt], 0, 0, 0);
    }
#pragma unroll
    for (int mt = 0; mt < 8; ++mt)
#pragma unroll
      for (int k = 0; k < 2; ++k) {
        const unsigned u = ABp[((mt << 1) + k) * BLOCK + tid];
        const float a0 = __builtin_bit_cast(float, u << 16);
        const float a1 = __builtin_bit_cast(float, u & 0xFFFF0000u);
        X[mt][2 * k]     = a0 * __builtin_amdgcn_rcpf(sum_v + X[mt][2 * k] + EPSF);
        X[mt][2 * k + 1] = a1 * __builtin_amdgcn_rcpf(sum_v + X[mt][2 * k + 1] + EPSF);
      }

    if (it < NITER - 1) {
      float rmu = 0.f;
#pragma unroll
      for (int mt = 0; mt < 8; ++mt)
#pragma unroll
        for (int q = 0; q < 4; ++q) rmu = fmaxf(rmu, X[mt][q]);
      rmu = fmaxf(rmu, __shfl_xor(rmu, 16));
      rmu = fmaxf(rmu, __shfl_xor(rmu, 32));
      const float inv2 = __builtin_amdgcn_rcpf(rmu);
      float su = 0.f;
#pragma unroll
      for (int mt = 0; mt < 8; ++mt)
#pragma unroll
        for (int q = 0; q < 4; ++q) su += X[mt][q];
#pragma unroll
      for (int s = 0; s < 4; ++s) {
        f32x4 u0, u1;
#pragma unroll
        for (int q = 0; q < 4; ++q) { u0[q] = X[2 * s][q] * inv2; u1[q] = X[2 * s + 1][q] * inv2; }
        uf[s] = packb(u0, u1);
      }
      su += __shfl_xor(su, 16);
      su += __shfl_xor(su, 32);
      sum_u = su * inv2;
    }
  }
  // X now holds final ru ; vf holds final v_stab ; wnorm term = ru*(T+eps).

  // ======== final: T = KM x V^T with KM = hi + lo bf16 split ========
  __syncthreads();
  for (int idx = tid; idx < 128 * 128; idx += BLOCK) {
    const int j = idx >> 7, i = idx & 127;
    const float cst = cost[idx];
    const float km  = cst * __builtin_amdgcn_exp2f(-cst * c1);
    const unsigned short khi = f2bf(km);
    const unsigned short klo = f2bf(km - bf2f((short)khi));
    const int w = swzw(j, i);
    EB[w] = (short)khi;
    EA[w] = (short)klo;
  }
  __syncthreads();

  f32x4 T[8];
#pragma unroll
  for (int mt = 0; mt < 8; ++mt) T[mt] = f32x4{0, 0, 0, 0};
#pragma unroll
  for (int s = 0; s < 4; ++s)
#pragma unroll
    for (int mt = 0; mt < 8; ++mt) {
      const s16x8 fh = afrag(EB, cl + (mt << 4), s << 5, h);
      const s16x8 fl = afrag(EA, cl + (mt << 4), s << 5, h);
      T[mt] = __builtin_amdgcn_mfma_f32_16x16x32_bf16(fh, vf[s], T[mt], 0, 0, 0);
      T[mt] = __builtin_amdgcn_mfma_f32_16x16x32_bf16(fl, vf[s], T[mt], 0, 0, 0);
    }

  // wnorm partial: sum ru*(T+eps)   (all stabilizers cancel exactly)
  float wsum = 0.f;
#pragma unroll
  for (int mt = 0; mt < 8; ++mt)
#pragma unroll
    for (int q = 0; q < 4; ++q)
      wsum += X[mt][q] * (T[mt][q] + EPSF);
  wsum += __shfl_xor(wsum, 1);
  wsum += __shfl_xor(wsum, 2);
  wsum += __shfl_xor(wsum, 4);
  wsum += __shfl_xor(wsum, 8);
  wsum += __shfl_xor(wsum, 16);
  wsum += __shfl_xor(wsum, 32);
  if (lane == 0) wred[wv] = wsum;

  // grad = (log2(ru) - rowmean(log2(ru))) * ln2 * lam / B  (m_v cancels)
  {
#pragma unroll
    for (int mt = 0; mt < 8; ++mt)
#pragma unroll
      for (int q = 0; q < 4; ++q)
        X[mt][q] = __builtin_amdgcn_logf(X[mt][q]);
    float sm = 0.f;
#pragma unroll
    for (int mt = 0; mt < 8; ++mt)
#pragma unroll
      for (int q = 0; q < 4; ++q) sm += X[mt][q];
    sm += __shfl_xor(sm, 16);
    sm += __shfl_xor(sm, 32);
    const float mean = sm * 0.0078125f;
    const int ro = 1 + rr + (h << 2);
#pragma unroll
    for (int mt = 0; mt < 8; ++mt)
#pragma unroll
      for (int q = 0; q < 4; ++q)
        out[ro + (mt << 4) + q] = (X[mt][q] - mean) * GRADS;
  }

  __syncthreads();
  if (tid == 0) {
    float s = 0.f;
#pragma unroll
    for (int w = 0; w < 8; ++w) s += wred[w];
    ws[blockIdx.x] = s;
  }
}

__global__ void sink_reduce(const float* __restrict__ ws, float* __restrict__ out)
{
  float s = 0.f;
  for (int i = threadIdx.x; i < 512; i += 256) s += ws[i];
  s += __shfl_xor(s, 1);
  s += __shfl_xor(s, 2);
  s += __shfl_xor(s, 4);
  s += __shfl_xor(s, 8);
  s += __shfl_xor(s, 16);
  s += __shfl_xor(s, 32);
  __shared__ float sm[4];
  if ((threadIdx.x & 63) == 0) sm[threadIdx.x >> 6] = s;
  __syncthreads();
  if (threadIdx.x == 0) out[0] = (sm[0] + sm[1] + sm[2] + sm[3]) * (1.0f / 65536.0f);
}

extern "C" void kernel_launch(void* const* d_in, const int* in_sizes, int n_in,
                              void* d_out, int out_size, void* d_ws, size_t ws_size,
                              hipStream_t stream)
{
  const float* pred = (const float*)d_in[0];
  const float* tgt  = (const float*)d_in[1];
  const float* cost = (const float*)d_in[2];
  float* out = (float*)d_out;
  float* ws  = (float*)d_ws;

  sink_mfma<<<512, BLOCK, 0, stream>>>(pred, tgt, cost, out, ws);
  sink_reduce<<<1, 256, 0, stream>>>(ws, out);
}

// Round 7
// 186.714 us; speedup vs baseline: 5.7539x; 1.3341x over previous
//
#include <hip/hip_runtime.h>

// Sinkhorn via MFMA, fully unnormalized inner loop.
// K = exp(-cost/100) = 1 + E, |E| <= 0.00995; u@K = sum(u) + u@E (bf16 MFMA
// carries only the 0.5% correction -> fp32-class accuracy).
//
// Round-7 insight: the Sinkhorn map is per-row 1-homogeneous; grad is
// row-centered log (scale cancels) and wnorm = sum u*(KM^T v) is invariant
// under u->au, v->v/a. With u0=1, unnormalized u,v stay in [1e-10,1e2] --
// well inside bf16 range. So ALL max-normalization (2 max-reduce chains,
// rcp, 64 muls/iter, and their register pressure) is deleted. Loop is:
//   v = b / (sum_u + E^T u);  u = a / (sum_v + E v + eps)
// NITER=3: full-iteration Hilbert contraction ~2.5e-5 -> fixed point by 2.
// E staging in two passes so E^T writes are bank-conflict-free (the old
// single-pass transpose write was 64-lanes-same-bank = the 1.4e7 conflict
// cycles seen in rocprof).

typedef __attribute__((ext_vector_type(4))) float f32x4;
typedef __attribute__((ext_vector_type(4))) short s16x4;
typedef __attribute__((ext_vector_type(8))) short s16x8;

constexpr int   NITER = 3;
constexpr int   BLOCK = 512;               // 8 waves, 16 rows each
constexpr float EPSF  = 1e-8f;
constexpr float LOG2E = 1.44269504088896340736f;
constexpr float LN2   = 0.69314718055994530942f;
constexpr float GRADS = LN2 * 100.0f / 65536.0f;   // ln2 * lam / B

__device__ __forceinline__ unsigned short f2bf(float x) {
  unsigned u = __builtin_bit_cast(unsigned, x);
  u += 0x7fffu + ((u >> 16) & 1u);
  return (unsigned short)(u >> 16);
}
__device__ __forceinline__ float bf2f(short h) {
  return __builtin_bit_cast(float, (unsigned)(unsigned short)h << 16);
}
__device__ __forceinline__ unsigned pack2(float lo, float hi) {
  return (unsigned)f2bf(lo) | ((unsigned)f2bf(hi) << 16);
}

// word index of element (r,c) of a 128x128 bf16 matrix, row-major, with a
// granule(8B)-XOR swizzle keyed on row bits 0..2 -> A-frag reads conflict-free.
__device__ __forceinline__ int swzw(int r, int c) {
  return (r << 7) + ((((c >> 2) ^ ((r & 7) << 2)) << 2) | (c & 3));
}

// A-fragment (16x16x32 bf16), k-permuted to match the chained D->B layout.
__device__ __forceinline__ s16x8 afrag(const short* M, int row, int kb, int h) {
  const int base = (row << 7) + ((((kb >> 2) + h) ^ ((row & 7) << 2)) << 2);
  const s16x4 lo = *reinterpret_cast<const s16x4*>(M + base);
  const s16x4 hi = *reinterpret_cast<const s16x4*>(M + (base ^ 16));
  s16x8 r;
  r[0] = lo[0]; r[1] = lo[1]; r[2] = lo[2]; r[3] = lo[3];
  r[4] = hi[0]; r[5] = hi[1]; r[6] = hi[2]; r[7] = hi[3];
  return r;
}

__device__ __forceinline__ s16x8 packb(const f32x4 a, const f32x4 b) {
  s16x8 r;
  r[0] = (short)f2bf(a[0]); r[1] = (short)f2bf(a[1]);
  r[2] = (short)f2bf(a[2]); r[3] = (short)f2bf(a[3]);
  r[4] = (short)f2bf(b[0]); r[5] = (short)f2bf(b[1]);
  r[6] = (short)f2bf(b[2]); r[7] = (short)f2bf(b[3]);
  return r;
}

__global__ __launch_bounds__(BLOCK, 2)
void sink_mfma(const float* __restrict__ pred,
               const float* __restrict__ tgt,
               const float* __restrict__ cost,
               float* __restrict__ out,
               float* __restrict__ ws)
{
  __shared__ __align__(16) short EA[128 * 128];   // E^T (MV1 A operand), 32KB
  __shared__ __align__(16) short EB[128 * 128];   // E   (MV2 A operand), 32KB
  __shared__ unsigned ABp[16 * BLOCK];            // a+eps bf16 pairs, 32KB
  __shared__ unsigned BBp[16 * BLOCK];            // b+eps bf16 pairs, 32KB
  __shared__ float wred[8];

  const int tid  = threadIdx.x;
  const int lane = tid & 63;
  const int wv   = tid >> 6;
  const int cl   = lane & 15;
  const int h    = lane >> 4;
  const float c1 = LOG2E * 0.01f;  // K = 2^(-cost*c1)

  // ---- stage E = K - 1 (bf16): two passes, both LDS-write conflict-free.
  for (int idx = tid; idx < 128 * 128; idx += BLOCK) {
    const int j = idx >> 7, i = idx & 127;           // coalesced cost read
    const float e = __builtin_amdgcn_exp2f(-cost[idx] * c1) - 1.0f;
    EB[swzw(j, i)] = (short)f2bf(e);                 // lanes vary i -> spread
  }
  for (int idx = tid; idx < 128 * 128; idx += BLOCK) {
    const int i = idx >> 7, j = idx & 127;           // gather read, L2-hot
    const float e = __builtin_amdgcn_exp2f(-cost[(j << 7) + i] * c1) - 1.0f;
    EA[swzw(i, j)] = (short)f2bf(e);                 // lanes vary j -> spread
  }

  const int row0 = (blockIdx.x << 7) + (wv << 4);  // 16 batch rows per wave
  const int rr   = (row0 + cl) << 7;

  // ---- a+eps, b+eps -> LDS as packed bf16 pairs.
  // elem e = mt*4+q lives at pair p = 2mt + (q>>1), half = q&1.
#pragma unroll
  for (int mt = 0; mt < 8; ++mt) {
    const float4 p4 = *reinterpret_cast<const float4*>(&pred[rr + (mt << 4) + (h << 2)]);
    const float4 t4 = *reinterpret_cast<const float4*>(&tgt [rr + (mt << 4) + (h << 2)]);
    ABp[((mt << 1) + 0) * BLOCK + tid] = pack2(p4.x + EPSF, p4.y + EPSF);
    ABp[((mt << 1) + 1) * BLOCK + tid] = pack2(p4.z + EPSF, p4.w + EPSF);
    BBp[((mt << 1) + 0) * BLOCK + tid] = pack2(t4.x + EPSF, t4.y + EPSF);
    BBp[((mt << 1) + 1) * BLOCK + tid] = pack2(t4.z + EPSF, t4.w + EPSF);
  }
  __syncthreads();

  // ---- state: u fragments (bf16 1.0), per-row sums (uniform across h)
  s16x8 uf[4], vf[4];
  {
    s16x8 ones;
#pragma unroll
    for (int k = 0; k < 8; ++k) ones[k] = (short)0x3F80;
#pragma unroll
    for (int s = 0; s < 4; ++s) uf[s] = ones;
  }
  float sum_u = 128.0f;
  float sum_v = 0.0f;
  f32x4 X[8];

  for (int it = 0; it < NITER; ++it) {
    // ======== MV1: X = E^T x U^T ; v = b / (sum_u + X) ========
#pragma unroll
    for (int mt = 0; mt < 8; ++mt) X[mt] = f32x4{0, 0, 0, 0};
#pragma unroll
    for (int s = 0; s < 4; ++s)
#pragma unroll
      for (int mt = 0; mt < 8; ++mt)
        X[mt] = __builtin_amdgcn_mfma_f32_16x16x32_bf16(
            afrag(EA, cl + (mt << 4), s << 5, h), uf[s], X[mt], 0, 0, 0);
    float sr = 0.f;
#pragma unroll
    for (int mt = 0; mt < 8; ++mt)
#pragma unroll
      for (int k = 0; k < 2; ++k) {
        const unsigned u = BBp[((mt << 1) + k) * BLOCK + tid];
        const float b0 = __builtin_bit_cast(float, u << 16);
        const float b1 = __builtin_bit_cast(float, u & 0xFFFF0000u);
        const float v0 = b0 * __builtin_amdgcn_rcpf(sum_u + X[mt][2 * k]);
        const float v1 = b1 * __builtin_amdgcn_rcpf(sum_u + X[mt][2 * k + 1]);
        X[mt][2 * k]     = v0;
        X[mt][2 * k + 1] = v1;
        sr += v0 + v1;
      }
#pragma unroll
    for (int s = 0; s < 4; ++s) vf[s] = packb(X[2 * s], X[2 * s + 1]);
    sr += __shfl_xor(sr, 16);
    sr += __shfl_xor(sr, 32);
    sum_v = sr;

    // ======== MV2: X = E x V^T ; u = a / (sum_v + X + eps) ========
#pragma unroll
    for (int mt = 0; mt < 8; ++mt) X[mt] = f32x4{0, 0, 0, 0};
#pragma unroll
    for (int s = 0; s < 4; ++s)
#pragma unroll
      for (int mt = 0; mt < 8; ++mt)
        X[mt] = __builtin_amdgcn_mfma_f32_16x16x32_bf16(
            afrag(EB, cl + (mt << 4), s << 5, h), vf[s], X[mt], 0, 0, 0);
    float su = 0.f;
#pragma unroll
    for (int mt = 0; mt < 8; ++mt)
#pragma unroll
      for (int k = 0; k < 2; ++k) {
        const unsigned u = ABp[((mt << 1) + k) * BLOCK + tid];
        const float a0 = __builtin_bit_cast(float, u << 16);
        const float a1 = __builtin_bit_cast(float, u & 0xFFFF0000u);
        const float r0 = a0 * __builtin_amdgcn_rcpf(sum_v + X[mt][2 * k] + EPSF);
        const float r1 = a1 * __builtin_amdgcn_rcpf(sum_v + X[mt][2 * k + 1] + EPSF);
        X[mt][2 * k]     = r0;
        X[mt][2 * k + 1] = r1;
        su += r0 + r1;
      }
#pragma unroll
    for (int s = 0; s < 4; ++s) uf[s] = packb(X[2 * s], X[2 * s + 1]);
    su += __shfl_xor(su, 16);
    su += __shfl_xor(su, 32);
    sum_u = su;
  }
  // X holds final u ; vf holds final v ; wnorm term = u*(T+eps).

  // ======== final: T = KM x V^T with KM = hi + lo bf16 split ========
  __syncthreads();
  for (int idx = tid; idx < 128 * 128; idx += BLOCK) {
    const int j = idx >> 7, i = idx & 127;
    const float cst = cost[idx];
    const float km  = cst * __builtin_amdgcn_exp2f(-cst * c1);
    const unsigned short khi = f2bf(km);
    const unsigned short klo = f2bf(km - bf2f((short)khi));
    const int w = swzw(j, i);                        // lanes vary i -> spread
    EB[w] = (short)khi;
    EA[w] = (short)klo;
  }
  __syncthreads();

  f32x4 T[8];
#pragma unroll
  for (int mt = 0; mt < 8; ++mt) T[mt] = f32x4{0, 0, 0, 0};
#pragma unroll
  for (int s = 0; s < 4; ++s)
#pragma unroll
    for (int mt = 0; mt < 8; ++mt) {
      T[mt] = __builtin_amdgcn_mfma_f32_16x16x32_bf16(
          afrag(EB, cl + (mt << 4), s << 5, h), vf[s], T[mt], 0, 0, 0);
      T[mt] = __builtin_amdgcn_mfma_f32_16x16x32_bf16(
          afrag(EA, cl + (mt << 4), s << 5, h), vf[s], T[mt], 0, 0, 0);
    }

  // wnorm partial: sum u*(T+eps)   (all row scales cancel exactly)
  float wsum = 0.f;
#pragma unroll
  for (int mt = 0; mt < 8; ++mt)
#pragma unroll
    for (int q = 0; q < 4; ++q)
      wsum += X[mt][q] * (T[mt][q] + EPSF);
  wsum += __shfl_xor(wsum, 1);
  wsum += __shfl_xor(wsum, 2);
  wsum += __shfl_xor(wsum, 4);
  wsum += __shfl_xor(wsum, 8);
  wsum += __shfl_xor(wsum, 16);
  wsum += __shfl_xor(wsum, 32);
  if (lane == 0) wred[wv] = wsum;

  // grad = (log2(u) - rowmean(log2(u))) * ln2 * lam / B  (row scale cancels)
  {
#pragma unroll
    for (int mt = 0; mt < 8; ++mt)
#pragma unroll
      for (int q = 0; q < 4; ++q)
        X[mt][q] = __builtin_amdgcn_logf(X[mt][q]);
    float sm = 0.f;
#pragma unroll
    for (int mt = 0; mt < 8; ++mt)
#pragma unroll
      for (int q = 0; q < 4; ++q) sm += X[mt][q];
    sm += __shfl_xor(sm, 16);
    sm += __shfl_xor(sm, 32);
    const float mean = sm * 0.0078125f;
    const int ro = 1 + rr + (h << 2);
#pragma unroll
    for (int mt = 0; mt < 8; ++mt)
#pragma unroll
      for (int q = 0; q < 4; ++q)
        out[ro + (mt << 4) + q] = (X[mt][q] - mean) * GRADS;
  }

  __syncthreads();
  if (tid == 0) {
    float s = 0.f;
#pragma unroll
    for (int w = 0; w < 8; ++w) s += wred[w];
    ws[blockIdx.x] = s;
  }
}

__global__ void sink_reduce(const float* __restrict__ ws, float* __restrict__ out)
{
  float s = 0.f;
  for (int i = threadIdx.x; i < 512; i += 256) s += ws[i];
  s += __shfl_xor(s, 1);
  s += __shfl_xor(s, 2);
  s += __shfl_xor(s, 4);
  s += __shfl_xor(s, 8);
  s += __shfl_xor(s, 16);
  s += __shfl_xor(s, 32);
  __shared__ float sm[4];
  if ((threadIdx.x & 63) == 0) sm[threadIdx.x >> 6] = s;
  __syncthreads();
  if (threadIdx.x == 0) out[0] = (sm[0] + sm[1] + sm[2] + sm[3]) * (1.0f / 65536.0f);
}

extern "C" void kernel_launch(void* const* d_in, const int* in_sizes, int n_in,
                              void* d_out, int out_size, void* d_ws, size_t ws_size,
                              hipStream_t stream)
{
  const float* pred = (const float*)d_in[0];
  const float* tgt  = (const float*)d_in[1];
  const float* cost = (const float*)d_in[2];
  float* out = (float*)d_out;
  float* ws  = (float*)d_ws;

  sink_mfma<<<512, BLOCK, 0, stream>>>(pred, tgt, cost, out, ws);
  sink_reduce<<<1, 256, 0, stream>>>(ws, out);
}

// Round 8
// 86.689 us; speedup vs baseline: 12.3930x; 2.1538x over previous
//
#include <hip/hip_runtime.h>

// Sinkhorn via MFMA, fully unnormalized inner loop.
// K = exp(-cost/100) = 1 + E, |E| <= 0.00995; u@K = sum(u) + u@E (bf16 MFMA
// carries only the 0.5% correction -> fp32-class accuracy).
//   v = b / (sum_u + E^T u);  u = a / (sum_v + E v + eps)
// Row scales cancel in both outputs (grad row-centered; wnorm = sum u*(KM^T v)
// invariant under u->au, v->v/a). NITER=3 reaches the fp32 fixed point.
//
// Round-8 change: rounds 2-7 all showed ~290 B/thread/iter of HBM scratch
// traffic (FETCH slope vs NITER) with every pipe idle. Cause: each MFMA phase
// is 32 afrag loads + 32 MFMAs with no ordering constraint; the pre-RA
// scheduler hoists ALL fragment loads above the MFMAs (256 VGPRs of
// fragments) -> spill of X/uf/vf around every phase. Fix: sched_group_barrier
// {2x DS_READ, 1x MFMA} after every MFMA pins the interleave at the
// scheduler level (source-level chunking in r5 was freely re-hoisted).

typedef __attribute__((ext_vector_type(4))) float f32x4;
typedef __attribute__((ext_vector_type(4))) short s16x4;
typedef __attribute__((ext_vector_type(8))) short s16x8;

constexpr int   NITER = 3;
constexpr int   BLOCK = 512;               // 8 waves, 16 rows each
constexpr float EPSF  = 1e-8f;
constexpr float LOG2E = 1.44269504088896340736f;
constexpr float LN2   = 0.69314718055994530942f;
constexpr float GRADS = LN2 * 100.0f / 65536.0f;   // ln2 * lam / B

// scheduler pin: allow exactly {2 ds_read, 1 mfma} per group, repeated
#define SGB_PAIR() do {                                      \
    __builtin_amdgcn_sched_group_barrier(0x100, 2, 0);       \
    __builtin_amdgcn_sched_group_barrier(0x008, 1, 0);       \
  } while (0)

__device__ __forceinline__ unsigned short f2bf(float x) {
  unsigned u = __builtin_bit_cast(unsigned, x);
  u += 0x7fffu + ((u >> 16) & 1u);
  return (unsigned short)(u >> 16);
}
__device__ __forceinline__ float bf2f(short h) {
  return __builtin_bit_cast(float, (unsigned)(unsigned short)h << 16);
}
__device__ __forceinline__ unsigned pack2(float lo, float hi) {
  return (unsigned)f2bf(lo) | ((unsigned)f2bf(hi) << 16);
}

// word index of element (r,c) of a 128x128 bf16 matrix, row-major, with a
// granule(8B)-XOR swizzle keyed on row bits 0..2 -> A-frag reads conflict-free.
__device__ __forceinline__ int swzw(int r, int c) {
  return (r << 7) + ((((c >> 2) ^ ((r & 7) << 2)) << 2) | (c & 3));
}

// A-fragment (16x16x32 bf16), k-permuted to match the chained D->B layout.
__device__ __forceinline__ s16x8 afrag(const short* M, int row, int kb, int h) {
  const int base = (row << 7) + ((((kb >> 2) + h) ^ ((row & 7) << 2)) << 2);
  const s16x4 lo = *reinterpret_cast<const s16x4*>(M + base);
  const s16x4 hi = *reinterpret_cast<const s16x4*>(M + (base ^ 16));
  s16x8 r;
  r[0] = lo[0]; r[1] = lo[1]; r[2] = lo[2]; r[3] = lo[3];
  r[4] = hi[0]; r[5] = hi[1]; r[6] = hi[2]; r[7] = hi[3];
  return r;
}

__device__ __forceinline__ s16x8 packb(const f32x4 a, const f32x4 b) {
  s16x8 r;
  r[0] = (short)f2bf(a[0]); r[1] = (short)f2bf(a[1]);
  r[2] = (short)f2bf(a[2]); r[3] = (short)f2bf(a[3]);
  r[4] = (short)f2bf(b[0]); r[5] = (short)f2bf(b[1]);
  r[6] = (short)f2bf(b[2]); r[7] = (short)f2bf(b[3]);
  return r;
}

__global__ __launch_bounds__(BLOCK, 2)
void sink_mfma(const float* __restrict__ pred,
               const float* __restrict__ tgt,
               const float* __restrict__ cost,
               float* __restrict__ out,
               float* __restrict__ ws)
{
  __shared__ __align__(16) short EA[128 * 128];   // E^T (MV1 A operand), 32KB
  __shared__ __align__(16) short EB[128 * 128];   // E   (MV2 A operand), 32KB
  __shared__ unsigned ABp[16 * BLOCK];            // a+eps bf16 pairs, 32KB
  __shared__ unsigned BBp[16 * BLOCK];            // b+eps bf16 pairs, 32KB
  __shared__ float wred[8];

  const int tid  = threadIdx.x;
  const int lane = tid & 63;
  const int wv   = tid >> 6;
  const int cl   = lane & 15;
  const int h    = lane >> 4;
  const float c1 = LOG2E * 0.01f;  // K = 2^(-cost*c1)

  // ---- stage E = K - 1 (bf16): two passes, both LDS-write conflict-free.
  for (int idx = tid; idx < 128 * 128; idx += BLOCK) {
    const int j = idx >> 7, i = idx & 127;           // coalesced cost read
    const float e = __builtin_amdgcn_exp2f(-cost[idx] * c1) - 1.0f;
    EB[swzw(j, i)] = (short)f2bf(e);                 // lanes vary i -> spread
  }
  for (int idx = tid; idx < 128 * 128; idx += BLOCK) {
    const int i = idx >> 7, j = idx & 127;           // gather read, L2-hot
    const float e = __builtin_amdgcn_exp2f(-cost[(j << 7) + i] * c1) - 1.0f;
    EA[swzw(i, j)] = (short)f2bf(e);                 // lanes vary j -> spread
  }

  const int row0 = (blockIdx.x << 7) + (wv << 4);  // 16 batch rows per wave
  const int rr   = (row0 + cl) << 7;

  // ---- a+eps, b+eps -> LDS as packed bf16 pairs.
  // elem e = mt*4+q lives at pair p = 2mt + (q>>1), half = q&1.
#pragma unroll
  for (int mt = 0; mt < 8; ++mt) {
    const float4 p4 = *reinterpret_cast<const float4*>(&pred[rr + (mt << 4) + (h << 2)]);
    const float4 t4 = *reinterpret_cast<const float4*>(&tgt [rr + (mt << 4) + (h << 2)]);
    ABp[((mt << 1) + 0) * BLOCK + tid] = pack2(p4.x + EPSF, p4.y + EPSF);
    ABp[((mt << 1) + 1) * BLOCK + tid] = pack2(p4.z + EPSF, p4.w + EPSF);
    BBp[((mt << 1) + 0) * BLOCK + tid] = pack2(t4.x + EPSF, t4.y + EPSF);
    BBp[((mt << 1) + 1) * BLOCK + tid] = pack2(t4.z + EPSF, t4.w + EPSF);
  }
  __syncthreads();

  // ---- state: u fragments (bf16 1.0), per-row sums (uniform across h)
  s16x8 uf[4], vf[4];
  {
    s16x8 ones;
#pragma unroll
    for (int k = 0; k < 8; ++k) ones[k] = (short)0x3F80;
#pragma unroll
    for (int s = 0; s < 4; ++s) uf[s] = ones;
  }
  float sum_u = 128.0f;
  float sum_v = 0.0f;
  f32x4 X[8];

  for (int it = 0; it < NITER; ++it) {
    // ======== MV1: X = E^T x U^T ; v = b / (sum_u + X) ========
#pragma unroll
    for (int mt = 0; mt < 8; ++mt) X[mt] = f32x4{0, 0, 0, 0};
#pragma unroll
    for (int s = 0; s < 4; ++s)
#pragma unroll
      for (int mt = 0; mt < 8; ++mt) {
        X[mt] = __builtin_amdgcn_mfma_f32_16x16x32_bf16(
            afrag(EA, cl + (mt << 4), s << 5, h), uf[s], X[mt], 0, 0, 0);
        SGB_PAIR();
      }
    float sr = 0.f;
#pragma unroll
    for (int mt = 0; mt < 8; ++mt)
#pragma unroll
      for (int k = 0; k < 2; ++k) {
        const unsigned u = BBp[((mt << 1) + k) * BLOCK + tid];
        const float b0 = __builtin_bit_cast(float, u << 16);
        const float b1 = __builtin_bit_cast(float, u & 0xFFFF0000u);
        const float v0 = b0 * __builtin_amdgcn_rcpf(sum_u + X[mt][2 * k]);
        const float v1 = b1 * __builtin_amdgcn_rcpf(sum_u + X[mt][2 * k + 1]);
        X[mt][2 * k]     = v0;
        X[mt][2 * k + 1] = v1;
        sr += v0 + v1;
      }
#pragma unroll
    for (int s = 0; s < 4; ++s) vf[s] = packb(X[2 * s], X[2 * s + 1]);
    sr += __shfl_xor(sr, 16);
    sr += __shfl_xor(sr, 32);
    sum_v = sr;

    // ======== MV2: X = E x V^T ; u = a / (sum_v + X + eps) ========
#pragma unroll
    for (int mt = 0; mt < 8; ++mt) X[mt] = f32x4{0, 0, 0, 0};
#pragma unroll
    for (int s = 0; s < 4; ++s)
#pragma unroll
      for (int mt = 0; mt < 8; ++mt) {
        X[mt] = __builtin_amdgcn_mfma_f32_16x16x32_bf16(
            afrag(EB, cl + (mt << 4), s << 5, h), vf[s], X[mt], 0, 0, 0);
        SGB_PAIR();
      }
    float su = 0.f;
#pragma unroll
    for (int mt = 0; mt < 8; ++mt)
#pragma unroll
      for (int k = 0; k < 2; ++k) {
        const unsigned u = ABp[((mt << 1) + k) * BLOCK + tid];
        const float a0 = __builtin_bit_cast(float, u << 16);
        const float a1 = __builtin_bit_cast(float, u & 0xFFFF0000u);
        const float r0 = a0 * __builtin_amdgcn_rcpf(sum_v + X[mt][2 * k] + EPSF);
        const float r1 = a1 * __builtin_amdgcn_rcpf(sum_v + X[mt][2 * k + 1] + EPSF);
        X[mt][2 * k]     = r0;
        X[mt][2 * k + 1] = r1;
        su += r0 + r1;
      }
#pragma unroll
    for (int s = 0; s < 4; ++s) uf[s] = packb(X[2 * s], X[2 * s + 1]);
    su += __shfl_xor(su, 16);
    su += __shfl_xor(su, 32);
    sum_u = su;
  }
  // X holds final u ; vf holds final v ; wnorm term = u*(T+eps).

  // ======== final: T = KM x V^T with KM = hi + lo bf16 split ========
  __syncthreads();
  for (int idx = tid; idx < 128 * 128; idx += BLOCK) {
    const int j = idx >> 7, i = idx & 127;
    const float cst = cost[idx];
    const float km  = cst * __builtin_amdgcn_exp2f(-cst * c1);
    const unsigned short khi = f2bf(km);
    const unsigned short klo = f2bf(km - bf2f((short)khi));
    const int w = swzw(j, i);                        // lanes vary i -> spread
    EB[w] = (short)khi;
    EA[w] = (short)klo;
  }
  __syncthreads();

  f32x4 T[8];
#pragma unroll
  for (int mt = 0; mt < 8; ++mt) T[mt] = f32x4{0, 0, 0, 0};
#pragma unroll
  for (int s = 0; s < 4; ++s)
#pragma unroll
    for (int mt = 0; mt < 8; ++mt) {
      T[mt] = __builtin_amdgcn_mfma_f32_16x16x32_bf16(
          afrag(EB, cl + (mt << 4), s << 5, h), vf[s], T[mt], 0, 0, 0);
      T[mt] = __builtin_amdgcn_mfma_f32_16x16x32_bf16(
          afrag(EA, cl + (mt << 4), s << 5, h), vf[s], T[mt], 0, 0, 0);
      __builtin_amdgcn_sched_group_barrier(0x100, 4, 0);
      __builtin_amdgcn_sched_group_barrier(0x008, 2, 0);
    }

  // wnorm partial: sum u*(T+eps)   (all row scales cancel exactly)
  float wsum = 0.f;
#pragma unroll
  for (int mt = 0; mt < 8; ++mt)
#pragma unroll
    for (int q = 0; q < 4; ++q)
      wsum += X[mt][q] * (T[mt][q] + EPSF);
  wsum += __shfl_xor(wsum, 1);
  wsum += __shfl_xor(wsum, 2);
  wsum += __shfl_xor(wsum, 4);
  wsum += __shfl_xor(wsum, 8);
  wsum += __shfl_xor(wsum, 16);
  wsum += __shfl_xor(wsum, 32);
  if (lane == 0) wred[wv] = wsum;

  // grad = (log2(u) - rowmean(log2(u))) * ln2 * lam / B  (row scale cancels)
  {
#pragma unroll
    for (int mt = 0; mt < 8; ++mt)
#pragma unroll
      for (int q = 0; q < 4; ++q)
        X[mt][q] = __builtin_amdgcn_logf(X[mt][q]);
    float sm = 0.f;
#pragma unroll
    for (int mt = 0; mt < 8; ++mt)
#pragma unroll
      for (int q = 0; q < 4; ++q) sm += X[mt][q];
    sm += __shfl_xor(sm, 16);
    sm += __shfl_xor(sm, 32);
    const float mean = sm * 0.0078125f;
    const int ro = 1 + rr + (h << 2);
#pragma unroll
    for (int mt = 0; mt < 8; ++mt)
#pragma unroll
      for (int q = 0; q < 4; ++q)
        out[ro + (mt << 4) + q] = (X[mt][q] - mean) * GRADS;
  }

  __syncthreads();
  if (tid == 0) {
    float s = 0.f;
#pragma unroll
    for (int w = 0; w < 8; ++w) s += wred[w];
    ws[blockIdx.x] = s;
  }
}

__global__ void sink_reduce(const float* __restrict__ ws, float* __restrict__ out)
{
  float s = 0.f;
  for (int i = threadIdx.x; i < 512; i += 256) s += ws[i];
  s += __shfl_xor(s, 1);
  s += __shfl_xor(s, 2);
  s += __shfl_xor(s, 4);
  s += __shfl_xor(s, 8);
  s += __shfl_xor(s, 16);
  s += __shfl_xor(s, 32);
  __shared__ float sm[4];
  if ((threadIdx.x & 63) == 0) sm[threadIdx.x >> 6] = s;
  __syncthreads();
  if (threadIdx.x == 0) out[0] = (sm[0] + sm[1] + sm[2] + sm[3]) * (1.0f / 65536.0f);
}

extern "C" void kernel_launch(void* const* d_in, const int* in_sizes, int n_in,
                              void* d_out, int out_size, void* d_ws, size_t ws_size,
                              hipStream_t stream)
{
  const float* pred = (const float*)d_in[0];
  const float* tgt  = (const float*)d_in[1];
  const float* cost = (const float*)d_in[2];
  float* out = (float*)d_out;
  float* ws  = (float*)d_ws;

  sink_mfma<<<512, BLOCK, 0, stream>>>(pred, tgt, cost, out, ws);
  sink_reduce<<<1, 256, 0, stream>>>(ws, out);
}